// Round 1
// baseline (1475.668 us; speedup 1.0000x reference)
//
#include <hip/hip_runtime.h>
#include <float.h>

__device__ __forceinline__ float wredmax(float v){
#pragma unroll
  for (int m = 32; m >= 1; m >>= 1) v = fmaxf(v, __shfl_xor(v, m, 64));
  return v;
}
__device__ __forceinline__ float wredsum(float v){
#pragma unroll
  for (int m = 32; m >= 1; m >>= 1) v += __shfl_xor(v, m, 64);
  return v;
}

// ---------------- CSR build ----------------
__global__ void k_hist(const int* __restrict__ ei, int E0, int total, int* __restrict__ deg){
  int i = blockIdx.x * blockDim.x + threadIdx.x;
  if (i >= total) return;
  int d = (i < E0) ? ei[E0 + i] : (i - E0);
  atomicAdd(&deg[d], 1);
}

__global__ __launch_bounds__(256) void k_scan1(const int* __restrict__ in, int* __restrict__ out,
                                               int* __restrict__ bsums, int n){
  __shared__ int lds[256];
  int t = threadIdx.x;
  int base = blockIdx.x * 1024 + t * 4;
  int v0 = (base + 0 < n) ? in[base + 0] : 0;
  int v1 = (base + 1 < n) ? in[base + 1] : 0;
  int v2 = (base + 2 < n) ? in[base + 2] : 0;
  int v3 = (base + 3 < n) ? in[base + 3] : 0;
  int ts = v0 + v1 + v2 + v3;
  int val = ts;
  lds[t] = ts; __syncthreads();
#pragma unroll
  for (int off = 1; off < 256; off <<= 1){
    int x = (t >= off) ? lds[t - off] : 0;
    __syncthreads();
    val += x;
    lds[t] = val;
    __syncthreads();
  }
  if (t == 255) bsums[blockIdx.x] = val;
  int run = val - ts;                 // exclusive prefix of this thread's chunk
  if (base + 0 < n) out[base + 0] = run; run += v0;
  if (base + 1 < n) out[base + 1] = run; run += v1;
  if (base + 2 < n) out[base + 2] = run; run += v2;
  if (base + 3 < n) out[base + 3] = run;
}

__global__ __launch_bounds__(1024) void k_scan2(int* __restrict__ bsums, int nb){
  __shared__ int lds[1024];
  int t = threadIdx.x;
  int v = (t < nb) ? bsums[t] : 0;
  int val = v;
  lds[t] = v; __syncthreads();
#pragma unroll
  for (int off = 1; off < 1024; off <<= 1){
    int x = (t >= off) ? lds[t - off] : 0;
    __syncthreads();
    val += x;
    lds[t] = val;
    __syncthreads();
  }
  if (t < nb) bsums[t] = val - v;     // exclusive
}

__global__ void k_scan3(int* __restrict__ offs, int* __restrict__ cursor,
                        const int* __restrict__ bsums, int n, int Etot){
  int i = blockIdx.x * blockDim.x + threadIdx.x;
  if (i < n){
    int o = offs[i] + bsums[i >> 10];
    offs[i] = o;
    cursor[i] = o;
  }
  if (i == 0) offs[n] = Etot;
}

__global__ void k_scatter(const int* __restrict__ ei, int E0, int total,
                          int* __restrict__ cursor, int* __restrict__ ssrc, int* __restrict__ seid){
  int i = blockIdx.x * blockDim.x + threadIdx.x;
  if (i >= total) return;
  int s, d;
  if (i < E0){ s = ei[i]; d = ei[E0 + i]; } else { s = i - E0; d = s; }
  int pos = atomicAdd(&cursor[d], 1);
  ssrc[pos] = s;
  seid[pos] = i;
}

// ---------------- fused linear + score kernels ----------------
// h1[n][64] = x[n][0:128] @ W1;  s_src[n] = h1[n]·a_src;  s_dst[n] = h1[n]·a_dst
__global__ __launch_bounds__(256) void k_linear1(const float* __restrict__ x, const float* __restrict__ W,
                                                 const float* __restrict__ a_s, const float* __restrict__ a_d,
                                                 float* __restrict__ h1, float* __restrict__ s_src,
                                                 float* __restrict__ s_dst, int n){
  __shared__ float wl[128 * 64];
  for (int i = threadIdx.x; i < 128 * 64; i += 256) wl[i] = W[i];
  __syncthreads();
  int lane = threadIdx.x & 63;
  int wid = (blockIdx.x * blockDim.x + threadIdx.x) >> 6;
  if (wid >= n) return;
  const float* xr = x + (size_t)wid * 128;
  float x0 = xr[lane], x1 = xr[64 + lane];
  float acc = 0.f;
#pragma unroll
  for (int k = 0; k < 64; ++k){
    float xk = __shfl(x0, k, 64);
    acc = fmaf(xk, wl[k * 64 + lane], acc);
  }
#pragma unroll
  for (int k = 0; k < 64; ++k){
    float xk = __shfl(x1, k, 64);
    acc = fmaf(xk, wl[(64 + k) * 64 + lane], acc);
  }
  h1[(size_t)wid * 64 + lane] = acc;
  float vs = wredsum(acc * a_s[lane]);
  float vd = wredsum(acc * a_d[lane]);
  if (lane == 0){ s_src[wid] = vs; s_dst[wid] = vd; }
}

// h2[n][32] = g1[n][0:64] @ W2 (two nodes per wave: half-waves)
__global__ __launch_bounds__(256) void k_linear2(const float* __restrict__ g, const float* __restrict__ W,
                                                 const float* __restrict__ a_s, const float* __restrict__ a_d,
                                                 float* __restrict__ h2, float* __restrict__ s_src,
                                                 float* __restrict__ s_dst, int n){
  __shared__ float wl[64 * 32];
  for (int i = threadIdx.x; i < 64 * 32; i += 256) wl[i] = W[i];
  __syncthreads();
  int lane = threadIdx.x & 63;
  int half = lane >> 5, fl = lane & 31;
  int wid = (blockIdx.x * blockDim.x + threadIdx.x) >> 6;
  if (wid * 2 >= n) return;
  int node = wid * 2 + half;
  bool valid = node < n;
  const float* gr = g + (size_t)node * 64;
  float x0 = valid ? gr[fl] : 0.f;
  float x1 = valid ? gr[32 + fl] : 0.f;
  float acc = 0.f;
#pragma unroll
  for (int k = 0; k < 32; ++k){
    float xk = __shfl(x0, (lane & 32) + k, 64);
    acc = fmaf(xk, wl[k * 32 + fl], acc);
  }
#pragma unroll
  for (int k = 0; k < 32; ++k){
    float xk = __shfl(x1, (lane & 32) + k, 64);
    acc = fmaf(xk, wl[(32 + k) * 32 + fl], acc);
  }
  if (valid) h2[(size_t)node * 32 + fl] = acc;
  float vs = acc * a_s[fl];
  float vd = acc * a_d[fl];
#pragma unroll
  for (int m = 16; m >= 1; m >>= 1){ vs += __shfl_xor(vs, m, 64); vd += __shfl_xor(vd, m, 64); }
  if (valid && fl == 0){ s_src[node] = vs; s_dst[node] = vd; }
}

// ---------------- segment softmax + aggregate ----------------
// one wave per dst node; CSR-ordered edges (atomic-free accumulation)
template<int F, bool ELU>
__global__ __launch_bounds__(256) void k_segment(
    const int* __restrict__ offs, const int* __restrict__ ssrc, const int* __restrict__ seid,
    const float* __restrict__ s_src, const float* __restrict__ s_dst,
    const float* __restrict__ h, const float* __restrict__ bias,
    float* __restrict__ out, float* __restrict__ alpha, int n)
{
  int wid = (blockIdx.x * blockDim.x + threadIdx.x) >> 6;
  if (wid >= n) return;
  int lane = threadIdx.x & 63;
  int beg = offs[wid], end = offs[wid + 1];
  float sd = s_dst[wid];

  // online (max, scaled-sum) per lane over this node's edges
  float m = -FLT_MAX, ss = 0.f;
  for (int j = beg + lane; j < end; j += 64){
    int s = ssrc[j];
    float e = s_src[s] + sd;
    e = (e > 0.f) ? e : 0.2f * e;
    if (e > m){ ss = ss * __expf(m - e) + 1.f; m = e; }
    else ss += __expf(e - m);
  }
  float gm = wredmax(m);
  float denom = wredsum(ss * __expf(m - gm));
  float inv = 1.f / denom;

  // accumulate weighted src features; lane = feature (F=64) or half-wave x 2 edges (F=32)
  constexpr int EPI = 64 / F;
  int half = lane / F;
  int fl = lane % F;
  float acc = 0.f;
  for (int j = beg; j < end; j += EPI){
    int jj = j + half;
    if (EPI == 1 || jj < end){
      int s = ssrc[jj];
      float e = s_src[s] + sd;
      e = (e > 0.f) ? e : 0.2f * e;
      float w = __expf(e - gm) * inv;
      acc = fmaf(w, h[(size_t)s * F + fl], acc);
      if (fl == 0) alpha[seid[jj]] = w;
    }
  }
  if (EPI == 2) acc += __shfl_xor(acc, 32, 64);
  if (lane < F){
    float o = acc + bias[fl];
    if (ELU) o = (o > 0.f) ? o : (__expf(o) - 1.f);
    out[(size_t)wid * F + fl] = o;
  }
}

// ---------------- launch ----------------
extern "C" void kernel_launch(void* const* d_in, const int* in_sizes, int n_in,
                              void* d_out, int out_size, void* d_ws, size_t ws_size,
                              hipStream_t stream)
{
  const float* x    = (const float*)d_in[0];
  const int*   ei   = (const int*)  d_in[1];
  const float* W1   = (const float*)d_in[2];
  const float* a_s1 = (const float*)d_in[3];
  const float* a_d1 = (const float*)d_in[4];
  const float* b1   = (const float*)d_in[5];
  const float* W2   = (const float*)d_in[6];
  const float* a_s2 = (const float*)d_in[7];
  const float* a_d2 = (const float*)d_in[8];
  const float* b2   = (const float*)d_in[9];

  const int N    = in_sizes[0] / 128;
  const int E0   = in_sizes[1] / 2;
  const int Etot = E0 + N;

  float* out_h2 = (float*)d_out;
  float* out_a1 = out_h2 + (size_t)N * 32;
  float* out_a2 = out_a1 + Etot;

  char* wsp = (char*)d_ws; size_t woff = 0;
  auto alloc = [&](size_t bytes)->void*{
    void* p = wsp + woff; woff += (bytes + 255) & ~(size_t)255; return p;
  };
  int*   deg    = (int*)  alloc((size_t)N * 4);
  int*   offs   = (int*)  alloc(((size_t)N + 1) * 4);
  int*   cursor = (int*)  alloc((size_t)N * 4);
  int*   bsums  = (int*)  alloc(4096);
  int*   ssrc   = (int*)  alloc((size_t)Etot * 4);
  int*   seid   = (int*)  alloc((size_t)Etot * 4);
  float* h1     = (float*)alloc((size_t)N * 64 * 4);
  float* g1     = (float*)alloc((size_t)N * 64 * 4);
  float* h2l    = (float*)alloc((size_t)N * 32 * 4);
  float* s1s    = (float*)alloc((size_t)N * 4);
  float* s1d    = (float*)alloc((size_t)N * 4);
  float* s2s    = (float*)alloc((size_t)N * 4);
  float* s2d    = (float*)alloc((size_t)N * 4);

  const int tb = 256;
  hipMemsetAsync(deg, 0, (size_t)N * 4, stream);
  k_hist<<<(Etot + tb - 1) / tb, tb, 0, stream>>>(ei, E0, Etot, deg);
  int nb = (N + 1023) / 1024;
  k_scan1<<<nb, 256, 0, stream>>>(deg, offs, bsums, N);
  k_scan2<<<1, 1024, 0, stream>>>(bsums, nb);
  k_scan3<<<(N + tb - 1) / tb, tb, 0, stream>>>(offs, cursor, bsums, N, Etot);
  k_scatter<<<(Etot + tb - 1) / tb, tb, 0, stream>>>(ei, E0, Etot, cursor, ssrc, seid);

  k_linear1<<<(N + 3) / 4, 256, 0, stream>>>(x, W1, a_s1, a_d1, h1, s1s, s1d, N);
  k_segment<64, true><<<(N + 3) / 4, 256, 0, stream>>>(offs, ssrc, seid, s1s, s1d, h1, b1, g1, out_a1, N);
  k_linear2<<<((N + 1) / 2 + 3) / 4, 256, 0, stream>>>(g1, W2, a_s2, a_d2, h2l, s2s, s2d, N);
  k_segment<32, false><<<(N + 3) / 4, 256, 0, stream>>>(offs, ssrc, seid, s2s, s2d, h2l, b2, out_h2, out_a2, N);
}

// Round 2
// 982.933 us; speedup vs baseline: 1.5013x; 1.5013x over previous
//
#include <hip/hip_runtime.h>
#include <float.h>

__device__ __forceinline__ float wredmax(float v){
#pragma unroll
  for (int m = 32; m >= 1; m >>= 1) v = fmaxf(v, __shfl_xor(v, m, 64));
  return v;
}
__device__ __forceinline__ float wredsum(float v){
#pragma unroll
  for (int m = 32; m >= 1; m >>= 1) v += __shfl_xor(v, m, 64);
  return v;
}

// ---------------- CSR build ----------------
__global__ void k_hist(const int* __restrict__ ei, int E0, int total, int* __restrict__ deg){
  int i = blockIdx.x * blockDim.x + threadIdx.x;
  if (i >= total) return;
  int d = (i < E0) ? ei[E0 + i] : (i - E0);
  atomicAdd(&deg[d], 1);
}

__global__ __launch_bounds__(256) void k_scan1(const int* __restrict__ in, int* __restrict__ out,
                                               int* __restrict__ bsums, int n){
  __shared__ int lds[256];
  int t = threadIdx.x;
  int base = blockIdx.x * 1024 + t * 4;
  int v0 = (base + 0 < n) ? in[base + 0] : 0;
  int v1 = (base + 1 < n) ? in[base + 1] : 0;
  int v2 = (base + 2 < n) ? in[base + 2] : 0;
  int v3 = (base + 3 < n) ? in[base + 3] : 0;
  int ts = v0 + v1 + v2 + v3;
  int val = ts;
  lds[t] = ts; __syncthreads();
#pragma unroll
  for (int off = 1; off < 256; off <<= 1){
    int x = (t >= off) ? lds[t - off] : 0;
    __syncthreads();
    val += x;
    lds[t] = val;
    __syncthreads();
  }
  if (t == 255) bsums[blockIdx.x] = val;
  int run = val - ts;
  if (base + 0 < n) out[base + 0] = run; run += v0;
  if (base + 1 < n) out[base + 1] = run; run += v1;
  if (base + 2 < n) out[base + 2] = run; run += v2;
  if (base + 3 < n) out[base + 3] = run;
}

__global__ __launch_bounds__(1024) void k_scan2(int* __restrict__ bsums, int nb){
  __shared__ int lds[1024];
  int t = threadIdx.x;
  int v = (t < nb) ? bsums[t] : 0;
  int val = v;
  lds[t] = v; __syncthreads();
#pragma unroll
  for (int off = 1; off < 1024; off <<= 1){
    int x = (t >= off) ? lds[t - off] : 0;
    __syncthreads();
    val += x;
    lds[t] = val;
    __syncthreads();
  }
  if (t < nb) bsums[t] = val - v;
}

__global__ void k_scan3(int* __restrict__ offs, int* __restrict__ cursor,
                        const int* __restrict__ bsums, int n, int Etot){
  int i = blockIdx.x * blockDim.x + threadIdx.x;
  if (i < n){
    int o = offs[i] + bsums[i >> 10];
    offs[i] = o;
    cursor[i] = o;
  }
  if (i == 0) offs[n] = Etot;
}

__global__ void k_scatter(const int* __restrict__ ei, int E0, int total,
                          int* __restrict__ cursor, int* __restrict__ ssrc){
  int i = blockIdx.x * blockDim.x + threadIdx.x;
  if (i >= total) return;
  int s, d;
  if (i < E0){ s = ei[i]; d = ei[E0 + i]; } else { s = i - E0; d = s; }
  int pos = atomicAdd(&cursor[d], 1);
  ssrc[pos] = s;
}

// ---------------- fused linear + score kernels ----------------
__global__ __launch_bounds__(256) void k_linear1(const float* __restrict__ x, const float* __restrict__ W,
                                                 const float* __restrict__ a_s, const float* __restrict__ a_d,
                                                 float* __restrict__ h1, float* __restrict__ s_src,
                                                 float* __restrict__ s_dst, int n){
  __shared__ float wl[128 * 64];
  for (int i = threadIdx.x; i < 128 * 64; i += 256) wl[i] = W[i];
  __syncthreads();
  int lane = threadIdx.x & 63;
  int wid = (blockIdx.x * blockDim.x + threadIdx.x) >> 6;
  if (wid >= n) return;
  const float* xr = x + (size_t)wid * 128;
  float x0 = xr[lane], x1 = xr[64 + lane];
  float acc = 0.f;
#pragma unroll
  for (int k = 0; k < 64; ++k){
    float xk = __shfl(x0, k, 64);
    acc = fmaf(xk, wl[k * 64 + lane], acc);
  }
#pragma unroll
  for (int k = 0; k < 64; ++k){
    float xk = __shfl(x1, k, 64);
    acc = fmaf(xk, wl[(64 + k) * 64 + lane], acc);
  }
  h1[(size_t)wid * 64 + lane] = acc;
  float vs = wredsum(acc * a_s[lane]);
  float vd = wredsum(acc * a_d[lane]);
  if (lane == 0){ s_src[wid] = vs; s_dst[wid] = vd; }
}

__global__ __launch_bounds__(256) void k_linear2(const float* __restrict__ g, const float* __restrict__ W,
                                                 const float* __restrict__ a_s, const float* __restrict__ a_d,
                                                 float* __restrict__ h2, float* __restrict__ s_src,
                                                 float* __restrict__ s_dst, int n){
  __shared__ float wl[64 * 32];
  for (int i = threadIdx.x; i < 64 * 32; i += 256) wl[i] = W[i];
  __syncthreads();
  int lane = threadIdx.x & 63;
  int half = lane >> 5, fl = lane & 31;
  int wid = (blockIdx.x * blockDim.x + threadIdx.x) >> 6;
  if (wid * 2 >= n) return;
  int node = wid * 2 + half;
  bool valid = node < n;
  const float* gr = g + (size_t)node * 64;
  float x0 = valid ? gr[fl] : 0.f;
  float x1 = valid ? gr[32 + fl] : 0.f;
  float acc = 0.f;
#pragma unroll
  for (int k = 0; k < 32; ++k){
    float xk = __shfl(x0, (lane & 32) + k, 64);
    acc = fmaf(xk, wl[k * 32 + fl], acc);
  }
#pragma unroll
  for (int k = 0; k < 32; ++k){
    float xk = __shfl(x1, (lane & 32) + k, 64);
    acc = fmaf(xk, wl[(32 + k) * 32 + fl], acc);
  }
  if (valid) h2[(size_t)node * 32 + fl] = acc;
  float vs = acc * a_s[fl];
  float vd = acc * a_d[fl];
#pragma unroll
  for (int m = 16; m >= 1; m >>= 1){ vs += __shfl_xor(vs, m, 64); vd += __shfl_xor(vd, m, 64); }
  if (valid && fl == 0){ s_src[node] = vs; s_dst[node] = vd; }
}

// ---------------- segment softmax + aggregate ----------------
// one wave per dst node; pass B uses edge-slots (ES edges in flight, float4 features)
template<int F, bool ELU>
__global__ __launch_bounds__(256) void k_segment(
    const int* __restrict__ offs, const int* __restrict__ ssrc,
    const float* __restrict__ s_src, const float* __restrict__ s_dst,
    const float* __restrict__ h, const float* __restrict__ bias,
    float* __restrict__ out, float* __restrict__ gmv, float* __restrict__ invv, int n)
{
  int wid = (blockIdx.x * blockDim.x + threadIdx.x) >> 6;
  if (wid >= n) return;
  int lane = threadIdx.x & 63;
  int beg = offs[wid], end = offs[wid + 1];
  float sd = s_dst[wid];

  // pass A: online (max, scaled-sum), lanes strided over edges
  float m = -FLT_MAX, ss = 0.f;
  for (int j = beg + lane; j < end; j += 64){
    int s = ssrc[j];
    float e = s_src[s] + sd;
    e = (e > 0.f) ? e : 0.2f * e;
    if (e > m){ ss = ss * __expf(m - e) + 1.f; m = e; }
    else ss += __expf(e - m);
  }
  float gm = wredmax(m);
  float denom = wredsum(ss * __expf(m - gm));
  float inv = 1.f / denom;
  if (lane == 0){ gmv[wid] = gm; invv[wid] = inv; }

  // pass B: FG lanes per edge (float4 features), ES edges concurrently
  constexpr int FG = F / 4;      // lanes per edge
  constexpr int ES = 64 / FG;    // edge slots in flight
  int es = lane / FG, fg = lane % FG;
  float ax = 0.f, ay = 0.f, az = 0.f, aw = 0.f;
#pragma unroll 2
  for (int j = beg; j < end; j += ES){
    int jj = j + es;
    if (jj < end){
      int s = ssrc[jj];
      float e = s_src[s] + sd;
      e = (e > 0.f) ? e : 0.2f * e;
      float w = __expf(e - gm) * inv;
      const float4 hv = *reinterpret_cast<const float4*>(h + (size_t)s * F + fg * 4);
      ax = fmaf(w, hv.x, ax); ay = fmaf(w, hv.y, ay);
      az = fmaf(w, hv.z, az); aw = fmaf(w, hv.w, aw);
    }
  }
#pragma unroll
  for (int mm = FG; mm < 64; mm <<= 1){
    ax += __shfl_xor(ax, mm, 64); ay += __shfl_xor(ay, mm, 64);
    az += __shfl_xor(az, mm, 64); aw += __shfl_xor(aw, mm, 64);
  }
  if (lane < FG){
    float4 o;
    o.x = ax + bias[fg * 4 + 0];
    o.y = ay + bias[fg * 4 + 1];
    o.z = az + bias[fg * 4 + 2];
    o.w = aw + bias[fg * 4 + 3];
    if (ELU){
      o.x = (o.x > 0.f) ? o.x : (__expf(o.x) - 1.f);
      o.y = (o.y > 0.f) ? o.y : (__expf(o.y) - 1.f);
      o.z = (o.z > 0.f) ? o.z : (__expf(o.z) - 1.f);
      o.w = (o.w > 0.f) ? o.w : (__expf(o.w) - 1.f);
    }
    *reinterpret_cast<float4*>(out + (size_t)wid * F + fg * 4) = o;
  }
}

// ---------------- alpha in original edge order (coalesced) ----------------
__global__ __launch_bounds__(256) void k_alpha(
    const int* __restrict__ ei, int E0, int total,
    const float* __restrict__ ss1, const float* __restrict__ sd1,
    const float* __restrict__ gm1, const float* __restrict__ inv1,
    const float* __restrict__ ss2, const float* __restrict__ sd2,
    const float* __restrict__ gm2, const float* __restrict__ inv2,
    float* __restrict__ a1, float* __restrict__ a2)
{
  int i = blockIdx.x * blockDim.x + threadIdx.x;
  if (i >= total) return;
  int s, d;
  if (i < E0){ s = ei[i]; d = ei[E0 + i]; } else { s = i - E0; d = s; }
  float e1 = ss1[s] + sd1[d];
  e1 = (e1 > 0.f) ? e1 : 0.2f * e1;
  a1[i] = __expf(e1 - gm1[d]) * inv1[d];
  float e2 = ss2[s] + sd2[d];
  e2 = (e2 > 0.f) ? e2 : 0.2f * e2;
  a2[i] = __expf(e2 - gm2[d]) * inv2[d];
}

// ---------------- launch ----------------
extern "C" void kernel_launch(void* const* d_in, const int* in_sizes, int n_in,
                              void* d_out, int out_size, void* d_ws, size_t ws_size,
                              hipStream_t stream)
{
  const float* x    = (const float*)d_in[0];
  const int*   ei   = (const int*)  d_in[1];
  const float* W1   = (const float*)d_in[2];
  const float* a_s1 = (const float*)d_in[3];
  const float* a_d1 = (const float*)d_in[4];
  const float* b1   = (const float*)d_in[5];
  const float* W2   = (const float*)d_in[6];
  const float* a_s2 = (const float*)d_in[7];
  const float* a_d2 = (const float*)d_in[8];
  const float* b2   = (const float*)d_in[9];

  const int N    = in_sizes[0] / 128;
  const int E0   = in_sizes[1] / 2;
  const int Etot = E0 + N;

  float* out_h2 = (float*)d_out;
  float* out_a1 = out_h2 + (size_t)N * 32;
  float* out_a2 = out_a1 + Etot;

  char* wsp = (char*)d_ws; size_t woff = 0;
  auto alloc = [&](size_t bytes)->void*{
    void* p = wsp + woff; woff += (bytes + 255) & ~(size_t)255; return p;
  };
  int*   deg    = (int*)  alloc((size_t)N * 4);
  int*   offs   = (int*)  alloc(((size_t)N + 1) * 4);
  int*   cursor = (int*)  alloc((size_t)N * 4);
  int*   bsums  = (int*)  alloc(4096);
  int*   ssrc   = (int*)  alloc((size_t)Etot * 4);
  float* h1     = (float*)alloc((size_t)N * 64 * 4);
  float* g1     = (float*)alloc((size_t)N * 64 * 4);
  float* h2l    = (float*)alloc((size_t)N * 32 * 4);
  float* s1s    = (float*)alloc((size_t)N * 4);
  float* s1d    = (float*)alloc((size_t)N * 4);
  float* s2s    = (float*)alloc((size_t)N * 4);
  float* s2d    = (float*)alloc((size_t)N * 4);
  float* gm1    = (float*)alloc((size_t)N * 4);
  float* inv1   = (float*)alloc((size_t)N * 4);
  float* gm2    = (float*)alloc((size_t)N * 4);
  float* inv2   = (float*)alloc((size_t)N * 4);

  const int tb = 256;
  hipMemsetAsync(deg, 0, (size_t)N * 4, stream);
  k_hist<<<(Etot + tb - 1) / tb, tb, 0, stream>>>(ei, E0, Etot, deg);
  int nb = (N + 1023) / 1024;
  k_scan1<<<nb, 256, 0, stream>>>(deg, offs, bsums, N);
  k_scan2<<<1, 1024, 0, stream>>>(bsums, nb);
  k_scan3<<<(N + tb - 1) / tb, tb, 0, stream>>>(offs, cursor, bsums, N, Etot);
  k_scatter<<<(Etot + tb - 1) / tb, tb, 0, stream>>>(ei, E0, Etot, cursor, ssrc);

  k_linear1<<<(N + 3) / 4, 256, 0, stream>>>(x, W1, a_s1, a_d1, h1, s1s, s1d, N);
  k_segment<64, true><<<(N + 3) / 4, 256, 0, stream>>>(offs, ssrc, s1s, s1d, h1, b1, g1, gm1, inv1, N);
  k_linear2<<<((N + 1) / 2 + 3) / 4, 256, 0, stream>>>(g1, W2, a_s2, a_d2, h2l, s2s, s2d, N);
  k_segment<32, false><<<(N + 3) / 4, 256, 0, stream>>>(offs, ssrc, s2s, s2d, h2l, b2, out_h2, gm2, inv2, N);
  k_alpha<<<(Etot + tb - 1) / tb, tb, 0, stream>>>(ei, E0, Etot, s1s, s1d, gm1, inv1, s2s, s2d, gm2, inv2, out_a1, out_a2);
}

// Round 3
// 851.651 us; speedup vs baseline: 1.7327x; 1.1541x over previous
//
#include <hip/hip_runtime.h>
#include <float.h>

__device__ __forceinline__ float wredmax(float v){
#pragma unroll
  for (int m = 32; m >= 1; m >>= 1) v = fmaxf(v, __shfl_xor(v, m, 64));
  return v;
}
__device__ __forceinline__ float wredsum(float v){
#pragma unroll
  for (int m = 32; m >= 1; m >>= 1) v += __shfl_xor(v, m, 64);
  return v;
}

// ---------------- CSR build ----------------
__global__ void k_hist(const int* __restrict__ ei, int E0, int total, int* __restrict__ deg){
  int i = blockIdx.x * blockDim.x + threadIdx.x;
  if (i >= total) return;
  int d = (i < E0) ? ei[E0 + i] : (i - E0);
  atomicAdd(&deg[d], 1);
}

__global__ __launch_bounds__(256) void k_scan1(const int* __restrict__ in, int* __restrict__ out,
                                               int* __restrict__ bsums, int n){
  __shared__ int lds[256];
  int t = threadIdx.x;
  int base = blockIdx.x * 1024 + t * 4;
  int v0 = (base + 0 < n) ? in[base + 0] : 0;
  int v1 = (base + 1 < n) ? in[base + 1] : 0;
  int v2 = (base + 2 < n) ? in[base + 2] : 0;
  int v3 = (base + 3 < n) ? in[base + 3] : 0;
  int ts = v0 + v1 + v2 + v3;
  int val = ts;
  lds[t] = ts; __syncthreads();
#pragma unroll
  for (int off = 1; off < 256; off <<= 1){
    int x = (t >= off) ? lds[t - off] : 0;
    __syncthreads();
    val += x;
    lds[t] = val;
    __syncthreads();
  }
  if (t == 255) bsums[blockIdx.x] = val;
  int run = val - ts;
  if (base + 0 < n) out[base + 0] = run; run += v0;
  if (base + 1 < n) out[base + 1] = run; run += v1;
  if (base + 2 < n) out[base + 2] = run; run += v2;
  if (base + 3 < n) out[base + 3] = run;
}

__global__ __launch_bounds__(1024) void k_scan2(int* __restrict__ bsums, int nb){
  __shared__ int lds[1024];
  int t = threadIdx.x;
  int v = (t < nb) ? bsums[t] : 0;
  int val = v;
  lds[t] = v; __syncthreads();
#pragma unroll
  for (int off = 1; off < 1024; off <<= 1){
    int x = (t >= off) ? lds[t - off] : 0;
    __syncthreads();
    val += x;
    lds[t] = val;
    __syncthreads();
  }
  if (t < nb) bsums[t] = val - v;
}

__global__ void k_scan3(int* __restrict__ offs, int* __restrict__ cursor,
                        const int* __restrict__ bsums, int n, int Etot){
  int i = blockIdx.x * blockDim.x + threadIdx.x;
  if (i < n){
    int o = offs[i] + bsums[i >> 10];
    offs[i] = o;
    cursor[i] = o;
  }
  if (i == 0) offs[n] = Etot;
}

// sliced scatter: slice = blockIdx.x & 7 -> lands on XCD (slice) under round-robin
// dispatch, so each slice's CSR window stays L2-resident on one XCD.
__global__ __launch_bounds__(256) void k_scatter(const int* __restrict__ ei, int E0, int total,
                          int N, int* __restrict__ cursor, int* __restrict__ ssrc){
  const int slice  = blockIdx.x & 7;
  const int chunk  = blockIdx.x >> 3;
  const int nchunk = gridDim.x >> 3;
  const int per = (total + nchunk - 1) / nchunk;
  const int lo = chunk * per;
  const int hi = min(lo + per, total);
  const int sw  = (N + 7) >> 3;
  const int slo = slice * sw;
  const int shi = slo + sw;
  for (int i = lo + threadIdx.x; i < hi; i += 256){
    int d = (i < E0) ? ei[E0 + i] : (i - E0);
    if (d >= slo && d < shi){
      int s = (i < E0) ? ei[i] : (i - E0);
      int pos = atomicAdd(&cursor[d], 1);
      ssrc[pos] = s;
    }
  }
}

// ---------------- fused linear + score kernels ----------------
__global__ __launch_bounds__(256) void k_linear1(const float* __restrict__ x, const float* __restrict__ W,
                                                 const float* __restrict__ a_s, const float* __restrict__ a_d,
                                                 float* __restrict__ h1, float* __restrict__ s_src,
                                                 float* __restrict__ s_dst, int n){
  __shared__ float wl[128 * 64];
  for (int i = threadIdx.x; i < 128 * 64; i += 256) wl[i] = W[i];
  __syncthreads();
  int lane = threadIdx.x & 63;
  int wid = (blockIdx.x * blockDim.x + threadIdx.x) >> 6;
  if (wid >= n) return;
  const float* xr = x + (size_t)wid * 128;
  float x0 = xr[lane], x1 = xr[64 + lane];
  float acc = 0.f;
#pragma unroll
  for (int k = 0; k < 64; ++k){
    float xk = __shfl(x0, k, 64);
    acc = fmaf(xk, wl[k * 64 + lane], acc);
  }
#pragma unroll
  for (int k = 0; k < 64; ++k){
    float xk = __shfl(x1, k, 64);
    acc = fmaf(xk, wl[(64 + k) * 64 + lane], acc);
  }
  h1[(size_t)wid * 64 + lane] = acc;
  float vs = wredsum(acc * a_s[lane]);
  float vd = wredsum(acc * a_d[lane]);
  if (lane == 0){ s_src[wid] = vs; s_dst[wid] = vd; }
}

__global__ __launch_bounds__(256) void k_linear2(const float* __restrict__ g, const float* __restrict__ W,
                                                 const float* __restrict__ a_s, const float* __restrict__ a_d,
                                                 float* __restrict__ h2, float* __restrict__ s_src,
                                                 float* __restrict__ s_dst, int n){
  __shared__ float wl[64 * 32];
  for (int i = threadIdx.x; i < 64 * 32; i += 256) wl[i] = W[i];
  __syncthreads();
  int lane = threadIdx.x & 63;
  int half = lane >> 5, fl = lane & 31;
  int wid = (blockIdx.x * blockDim.x + threadIdx.x) >> 6;
  if (wid * 2 >= n) return;
  int node = wid * 2 + half;
  bool valid = node < n;
  const float* gr = g + (size_t)node * 64;
  float x0 = valid ? gr[fl] : 0.f;
  float x1 = valid ? gr[32 + fl] : 0.f;
  float acc = 0.f;
#pragma unroll
  for (int k = 0; k < 32; ++k){
    float xk = __shfl(x0, (lane & 32) + k, 64);
    acc = fmaf(xk, wl[k * 32 + fl], acc);
  }
#pragma unroll
  for (int k = 0; k < 32; ++k){
    float xk = __shfl(x1, (lane & 32) + k, 64);
    acc = fmaf(xk, wl[(32 + k) * 32 + fl], acc);
  }
  if (valid) h2[(size_t)node * 32 + fl] = acc;
  float vs = acc * a_s[fl];
  float vd = acc * a_d[fl];
#pragma unroll
  for (int m = 16; m >= 1; m >>= 1){ vs += __shfl_xor(vs, m, 64); vd += __shfl_xor(vd, m, 64); }
  if (valid && fl == 0){ s_src[node] = vs; s_dst[node] = vd; }
}

// ---------------- segment softmax + aggregate ----------------
template<int F, bool ELU>
__global__ __launch_bounds__(256) void k_segment(
    const int* __restrict__ offs, const int* __restrict__ ssrc,
    const float* __restrict__ s_src, const float* __restrict__ s_dst,
    const float* __restrict__ h, const float* __restrict__ bias,
    float* __restrict__ out, float* __restrict__ gmv, float* __restrict__ invv, int n)
{
  int wid = (blockIdx.x * blockDim.x + threadIdx.x) >> 6;
  if (wid >= n) return;
  int lane = threadIdx.x & 63;
  int beg = offs[wid], end = offs[wid + 1];
  float sd = s_dst[wid];

  // pass A: online (max, scaled-sum), lanes strided over edges
  float m = -FLT_MAX, ss = 0.f;
  for (int j = beg + lane; j < end; j += 64){
    int s = ssrc[j];
    float e = s_src[s] + sd;
    e = (e > 0.f) ? e : 0.2f * e;
    if (e > m){ ss = ss * __expf(m - e) + 1.f; m = e; }
    else ss += __expf(e - m);
  }
  float gm = wredmax(m);
  float denom = wredsum(ss * __expf(m - gm));
  float inv = 1.f / denom;
  if (lane == 0){ gmv[wid] = gm; invv[wid] = inv; }

  // pass B: FG lanes per edge (float4 features), ES edges concurrently
  constexpr int FG = F / 4;      // lanes per edge
  constexpr int ES = 64 / FG;    // edge slots in flight
  int es = lane / FG, fg = lane % FG;
  float ax = 0.f, ay = 0.f, az = 0.f, aw = 0.f;
#pragma unroll 2
  for (int j = beg; j < end; j += ES){
    int jj = j + es;
    if (jj < end){
      int s = ssrc[jj];
      float e = s_src[s] + sd;
      e = (e > 0.f) ? e : 0.2f * e;
      float w = __expf(e - gm) * inv;
      const float4 hv = *reinterpret_cast<const float4*>(h + (size_t)s * F + fg * 4);
      ax = fmaf(w, hv.x, ax); ay = fmaf(w, hv.y, ay);
      az = fmaf(w, hv.z, az); aw = fmaf(w, hv.w, aw);
    }
  }
#pragma unroll
  for (int mm = FG; mm < 64; mm <<= 1){
    ax += __shfl_xor(ax, mm, 64); ay += __shfl_xor(ay, mm, 64);
    az += __shfl_xor(az, mm, 64); aw += __shfl_xor(aw, mm, 64);
  }
  if (lane < FG){
    float4 o;
    o.x = ax + bias[fg * 4 + 0];
    o.y = ay + bias[fg * 4 + 1];
    o.z = az + bias[fg * 4 + 2];
    o.w = aw + bias[fg * 4 + 3];
    if (ELU){
      o.x = (o.x > 0.f) ? o.x : (__expf(o.x) - 1.f);
      o.y = (o.y > 0.f) ? o.y : (__expf(o.y) - 1.f);
      o.z = (o.z > 0.f) ? o.z : (__expf(o.z) - 1.f);
      o.w = (o.w > 0.f) ? o.w : (__expf(o.w) - 1.f);
    }
    *reinterpret_cast<float4*>(out + (size_t)wid * F + fg * 4) = o;
  }
}

// ---------------- alpha in original edge order (coalesced) ----------------
__global__ __launch_bounds__(256) void k_alpha(
    const int* __restrict__ ei, int E0, int total,
    const float* __restrict__ ss1, const float* __restrict__ sd1,
    const float* __restrict__ gm1, const float* __restrict__ inv1,
    const float* __restrict__ ss2, const float* __restrict__ sd2,
    const float* __restrict__ gm2, const float* __restrict__ inv2,
    float* __restrict__ a1, float* __restrict__ a2)
{
  int i = blockIdx.x * blockDim.x + threadIdx.x;
  if (i >= total) return;
  int s, d;
  if (i < E0){ s = ei[i]; d = ei[E0 + i]; } else { s = i - E0; d = s; }
  float e1 = ss1[s] + sd1[d];
  e1 = (e1 > 0.f) ? e1 : 0.2f * e1;
  a1[i] = __expf(e1 - gm1[d]) * inv1[d];
  float e2 = ss2[s] + sd2[d];
  e2 = (e2 > 0.f) ? e2 : 0.2f * e2;
  a2[i] = __expf(e2 - gm2[d]) * inv2[d];
}

// ---------------- launch ----------------
extern "C" void kernel_launch(void* const* d_in, const int* in_sizes, int n_in,
                              void* d_out, int out_size, void* d_ws, size_t ws_size,
                              hipStream_t stream)
{
  const float* x    = (const float*)d_in[0];
  const int*   ei   = (const int*)  d_in[1];
  const float* W1   = (const float*)d_in[2];
  const float* a_s1 = (const float*)d_in[3];
  const float* a_d1 = (const float*)d_in[4];
  const float* b1   = (const float*)d_in[5];
  const float* W2   = (const float*)d_in[6];
  const float* a_s2 = (const float*)d_in[7];
  const float* a_d2 = (const float*)d_in[8];
  const float* b2   = (const float*)d_in[9];

  const int N    = in_sizes[0] / 128;
  const int E0   = in_sizes[1] / 2;
  const int Etot = E0 + N;

  float* out_h2 = (float*)d_out;
  float* out_a1 = out_h2 + (size_t)N * 32;
  float* out_a2 = out_a1 + Etot;

  char* wsp = (char*)d_ws; size_t woff = 0;
  auto alloc = [&](size_t bytes)->void*{
    void* p = wsp + woff; woff += (bytes + 255) & ~(size_t)255; return p;
  };
  int*   deg    = (int*)  alloc((size_t)N * 4);
  int*   offs   = (int*)  alloc(((size_t)N + 1) * 4);
  int*   cursor = (int*)  alloc((size_t)N * 4);
  int*   bsums  = (int*)  alloc(4096);
  int*   ssrc   = (int*)  alloc((size_t)Etot * 4);
  float* h1     = (float*)alloc((size_t)N * 64 * 4);
  float* g1     = (float*)alloc((size_t)N * 64 * 4);
  float* h2l    = (float*)alloc((size_t)N * 32 * 4);
  float* s1s    = (float*)alloc((size_t)N * 4);
  float* s1d    = (float*)alloc((size_t)N * 4);
  float* s2s    = (float*)alloc((size_t)N * 4);
  float* s2d    = (float*)alloc((size_t)N * 4);
  float* gm1    = (float*)alloc((size_t)N * 4);
  float* inv1   = (float*)alloc((size_t)N * 4);
  float* gm2    = (float*)alloc((size_t)N * 4);
  float* inv2   = (float*)alloc((size_t)N * 4);

  const int tb = 256;
  hipMemsetAsync(deg, 0, (size_t)N * 4, stream);
  k_hist<<<(Etot + tb - 1) / tb, tb, 0, stream>>>(ei, E0, Etot, deg);
  int nb = (N + 1023) / 1024;
  k_scan1<<<nb, 256, 0, stream>>>(deg, offs, bsums, N);
  k_scan2<<<1, 1024, 0, stream>>>(bsums, nb);
  k_scan3<<<(N + tb - 1) / tb, tb, 0, stream>>>(offs, cursor, bsums, N, Etot);
  k_scatter<<<1024 * 8, 256, 0, stream>>>(ei, E0, Etot, N, cursor, ssrc);

  k_linear1<<<(N + 3) / 4, 256, 0, stream>>>(x, W1, a_s1, a_d1, h1, s1s, s1d, N);
  k_segment<64, true><<<(N + 3) / 4, 256, 0, stream>>>(offs, ssrc, s1s, s1d, h1, b1, g1, gm1, inv1, N);
  k_linear2<<<((N + 1) / 2 + 3) / 4, 256, 0, stream>>>(g1, W2, a_s2, a_d2, h2l, s2s, s2d, N);
  k_segment<32, false><<<(N + 3) / 4, 256, 0, stream>>>(offs, ssrc, s2s, s2d, h2l, b2, out_h2, gm2, inv2, N);
  k_alpha<<<(Etot + tb - 1) / tb, tb, 0, stream>>>(ei, E0, Etot, s1s, s1d, gm1, inv1, s2s, s2d, gm2, inv2, out_a1, out_a2);
}

// Round 4
// 676.083 us; speedup vs baseline: 2.1827x; 1.2597x over previous
//
#include <hip/hip_runtime.h>
#include <float.h>

__device__ __forceinline__ float wredmax(float v){
#pragma unroll
  for (int m = 32; m >= 1; m >>= 1) v = fmaxf(v, __shfl_xor(v, m, 64));
  return v;
}
__device__ __forceinline__ float wredsum(float v){
#pragma unroll
  for (int m = 32; m >= 1; m >>= 1) v += __shfl_xor(v, m, 64);
  return v;
}

// ---------------- CSR build ----------------
__global__ void k_hist(const int* __restrict__ ei, int E0, int total, int* __restrict__ deg){
  int i = blockIdx.x * blockDim.x + threadIdx.x;
  if (i >= total) return;
  int d = (i < E0) ? ei[E0 + i] : (i - E0);
  atomicAdd(&deg[d], 1);
}

__global__ __launch_bounds__(256) void k_scan1(const int* __restrict__ in, int* __restrict__ out,
                                               int* __restrict__ bsums, int n){
  __shared__ int lds[256];
  int t = threadIdx.x;
  int base = blockIdx.x * 1024 + t * 4;
  int v0 = (base + 0 < n) ? in[base + 0] : 0;
  int v1 = (base + 1 < n) ? in[base + 1] : 0;
  int v2 = (base + 2 < n) ? in[base + 2] : 0;
  int v3 = (base + 3 < n) ? in[base + 3] : 0;
  int ts = v0 + v1 + v2 + v3;
  int val = ts;
  lds[t] = ts; __syncthreads();
#pragma unroll
  for (int off = 1; off < 256; off <<= 1){
    int x = (t >= off) ? lds[t - off] : 0;
    __syncthreads();
    val += x;
    lds[t] = val;
    __syncthreads();
  }
  if (t == 255) bsums[blockIdx.x] = val;
  int run = val - ts;
  if (base + 0 < n) out[base + 0] = run; run += v0;
  if (base + 1 < n) out[base + 1] = run; run += v1;
  if (base + 2 < n) out[base + 2] = run; run += v2;
  if (base + 3 < n) out[base + 3] = run;
}

__global__ __launch_bounds__(1024) void k_scan2(int* __restrict__ bsums, int nb){
  __shared__ int lds[1024];
  int t = threadIdx.x;
  int v = (t < nb) ? bsums[t] : 0;
  int val = v;
  lds[t] = v; __syncthreads();
#pragma unroll
  for (int off = 1; off < 1024; off <<= 1){
    int x = (t >= off) ? lds[t - off] : 0;
    __syncthreads();
    val += x;
    lds[t] = val;
    __syncthreads();
  }
  if (t < nb) bsums[t] = val - v;
}

__global__ void k_scan3(int* __restrict__ offs, int* __restrict__ cursor,
                        const int* __restrict__ bsums, int n, int Etot){
  int i = blockIdx.x * blockDim.x + threadIdx.x;
  if (i < n){
    int o = offs[i] + bsums[i >> 10];
    offs[i] = o;
    cursor[i] = o;
  }
  if (i == 0) offs[n] = Etot;
}

// sliced scatter: slice = blockIdx.x & 7 -> lands on XCD (slice) under round-robin
// dispatch, so each slice's CSR window stays L2-resident on one XCD.
__global__ __launch_bounds__(256) void k_scatter(const int* __restrict__ ei, int E0, int total,
                          int N, int* __restrict__ cursor, int* __restrict__ ssrc){
  const int slice  = blockIdx.x & 7;
  const int chunk  = blockIdx.x >> 3;
  const int nchunk = gridDim.x >> 3;
  const int per = (total + nchunk - 1) / nchunk;
  const int lo = chunk * per;
  const int hi = min(lo + per, total);
  const int sw  = (N + 7) >> 3;
  const int slo = slice * sw;
  const int shi = slo + sw;
  for (int i = lo + threadIdx.x; i < hi; i += 256){
    int d = (i < E0) ? ei[E0 + i] : (i - E0);
    if (d >= slo && d < shi){
      int s = (i < E0) ? ei[i] : (i - E0);
      int pos = atomicAdd(&cursor[d], 1);
      ssrc[pos] = s;
    }
  }
}

// ---------------- fused linear + score kernel ----------------
// thread-per-node: acc[FOUT] in VGPRs, W read with wave-uniform index (s_load),
// x staged transposed into LDS (conflict-free both directions).
template<int FIN, int FOUT>
__global__ __launch_bounds__(256) void k_linear(
    const float* __restrict__ x, const float* __restrict__ W,
    const float* __restrict__ a_s, const float* __restrict__ a_d,
    float* __restrict__ h, float* __restrict__ s_src, float* __restrict__ s_dst, int n)
{
  constexpr int CK = 32;                 // k-chunk
  constexpr int NCH = FIN / CK;
  __shared__ float xs[CK][257];
  const int tid = threadIdx.x;
  const int node0 = blockIdx.x * 256;
  const int node = node0 + tid;
  const int nrow = min(256, n - node0);

  float acc[FOUT];
#pragma unroll
  for (int o = 0; o < FOUT; ++o) acc[o] = 0.f;

  for (int kc = 0; kc < NCH; ++kc){
    __syncthreads();
    // stage x[node0..node0+255][kc*CK..+CK-1] transposed into xs[k][row]
    const int r0 = tid >> 3;             // 0..31
    const int c4 = tid & 7;              // float4 index within chunk (8*4=32 cols)
#pragma unroll
    for (int p = 0; p < 8; ++p){
      int row = p * 32 + r0;
      if (row < nrow){
        const float4 v = *reinterpret_cast<const float4*>(
            x + (size_t)(node0 + row) * FIN + kc * CK + c4 * 4);
        xs[c4 * 4 + 0][row] = v.x;
        xs[c4 * 4 + 1][row] = v.y;
        xs[c4 * 4 + 2][row] = v.z;
        xs[c4 * 4 + 3][row] = v.w;
      }
    }
    __syncthreads();
#pragma unroll 8
    for (int k = 0; k < CK; ++k){
      float xv = xs[k][tid];
      const int kg = kc * CK + k;
#pragma unroll
      for (int o4 = 0; o4 < FOUT / 4; ++o4){
        // thread-uniform index -> scalar loads on the SMEM pipe
        const float4 w = *reinterpret_cast<const float4*>(W + (size_t)kg * FOUT + o4 * 4);
        acc[o4 * 4 + 0] = fmaf(xv, w.x, acc[o4 * 4 + 0]);
        acc[o4 * 4 + 1] = fmaf(xv, w.y, acc[o4 * 4 + 1]);
        acc[o4 * 4 + 2] = fmaf(xv, w.z, acc[o4 * 4 + 2]);
        acc[o4 * 4 + 3] = fmaf(xv, w.w, acc[o4 * 4 + 3]);
      }
    }
  }

  if (node < n){
    float vs = 0.f, vd = 0.f;
#pragma unroll
    for (int o4 = 0; o4 < FOUT / 4; ++o4){
      float4 o;
      o.x = acc[o4 * 4 + 0]; o.y = acc[o4 * 4 + 1];
      o.z = acc[o4 * 4 + 2]; o.w = acc[o4 * 4 + 3];
      *reinterpret_cast<float4*>(h + (size_t)node * FOUT + o4 * 4) = o;
      const float4 as = *reinterpret_cast<const float4*>(a_s + o4 * 4);
      const float4 ad = *reinterpret_cast<const float4*>(a_d + o4 * 4);
      vs += o.x * as.x + o.y * as.y + o.z * as.z + o.w * as.w;
      vd += o.x * ad.x + o.y * ad.y + o.z * ad.z + o.w * ad.w;
    }
    s_src[node] = vs;
    s_dst[node] = vd;
  }
}

// ---------------- segment softmax + aggregate ----------------
template<int F, bool ELU>
__global__ __launch_bounds__(256) void k_segment(
    const int* __restrict__ offs, const int* __restrict__ ssrc,
    const float* __restrict__ s_src, const float* __restrict__ s_dst,
    const float* __restrict__ h, const float* __restrict__ bias,
    float* __restrict__ out, float* __restrict__ gmv, float* __restrict__ invv, int n)
{
  int wid = (blockIdx.x * blockDim.x + threadIdx.x) >> 6;
  if (wid >= n) return;
  int lane = threadIdx.x & 63;
  int beg = offs[wid], end = offs[wid + 1];
  float sd = s_dst[wid];

  // pass A: online (max, scaled-sum), lanes strided over edges
  float m = -FLT_MAX, ss = 0.f;
  for (int j = beg + lane; j < end; j += 64){
    int s = ssrc[j];
    float e = s_src[s] + sd;
    e = (e > 0.f) ? e : 0.2f * e;
    if (e > m){ ss = ss * __expf(m - e) + 1.f; m = e; }
    else ss += __expf(e - m);
  }
  float gm = wredmax(m);
  float denom = wredsum(ss * __expf(m - gm));
  float inv = 1.f / denom;
  if (lane == 0){ gmv[wid] = gm; invv[wid] = inv; }

  // pass B: FG lanes per edge (float4 features), ES edges concurrently
  constexpr int FG = F / 4;      // lanes per edge
  constexpr int ES = 64 / FG;    // edge slots in flight
  int es = lane / FG, fg = lane % FG;
  float ax = 0.f, ay = 0.f, az = 0.f, aw = 0.f;
#pragma unroll 2
  for (int j = beg; j < end; j += ES){
    int jj = j + es;
    if (jj < end){
      int s = ssrc[jj];
      float e = s_src[s] + sd;
      e = (e > 0.f) ? e : 0.2f * e;
      float w = __expf(e - gm) * inv;
      const float4 hv = *reinterpret_cast<const float4*>(h + (size_t)s * F + fg * 4);
      ax = fmaf(w, hv.x, ax); ay = fmaf(w, hv.y, ay);
      az = fmaf(w, hv.z, az); aw = fmaf(w, hv.w, aw);
    }
  }
#pragma unroll
  for (int mm = FG; mm < 64; mm <<= 1){
    ax += __shfl_xor(ax, mm, 64); ay += __shfl_xor(ay, mm, 64);
    az += __shfl_xor(az, mm, 64); aw += __shfl_xor(aw, mm, 64);
  }
  if (lane < FG){
    float4 o;
    o.x = ax + bias[fg * 4 + 0];
    o.y = ay + bias[fg * 4 + 1];
    o.z = az + bias[fg * 4 + 2];
    o.w = aw + bias[fg * 4 + 3];
    if (ELU){
      o.x = (o.x > 0.f) ? o.x : (__expf(o.x) - 1.f);
      o.y = (o.y > 0.f) ? o.y : (__expf(o.y) - 1.f);
      o.z = (o.z > 0.f) ? o.z : (__expf(o.z) - 1.f);
      o.w = (o.w > 0.f) ? o.w : (__expf(o.w) - 1.f);
    }
    *reinterpret_cast<float4*>(out + (size_t)wid * F + fg * 4) = o;
  }
}

// ---------------- alpha in original edge order (coalesced) ----------------
__global__ __launch_bounds__(256) void k_alpha(
    const int* __restrict__ ei, int E0, int total,
    const float* __restrict__ ss1, const float* __restrict__ sd1,
    const float* __restrict__ gm1, const float* __restrict__ inv1,
    const float* __restrict__ ss2, const float* __restrict__ sd2,
    const float* __restrict__ gm2, const float* __restrict__ inv2,
    float* __restrict__ a1, float* __restrict__ a2)
{
  int i = blockIdx.x * blockDim.x + threadIdx.x;
  if (i >= total) return;
  int s, d;
  if (i < E0){ s = ei[i]; d = ei[E0 + i]; } else { s = i - E0; d = s; }
  float e1 = ss1[s] + sd1[d];
  e1 = (e1 > 0.f) ? e1 : 0.2f * e1;
  a1[i] = __expf(e1 - gm1[d]) * inv1[d];
  float e2 = ss2[s] + sd2[d];
  e2 = (e2 > 0.f) ? e2 : 0.2f * e2;
  a2[i] = __expf(e2 - gm2[d]) * inv2[d];
}

// ---------------- launch ----------------
extern "C" void kernel_launch(void* const* d_in, const int* in_sizes, int n_in,
                              void* d_out, int out_size, void* d_ws, size_t ws_size,
                              hipStream_t stream)
{
  const float* x    = (const float*)d_in[0];
  const int*   ei   = (const int*)  d_in[1];
  const float* W1   = (const float*)d_in[2];
  const float* a_s1 = (const float*)d_in[3];
  const float* a_d1 = (const float*)d_in[4];
  const float* b1   = (const float*)d_in[5];
  const float* W2   = (const float*)d_in[6];
  const float* a_s2 = (const float*)d_in[7];
  const float* a_d2 = (const float*)d_in[8];
  const float* b2   = (const float*)d_in[9];

  const int N    = in_sizes[0] / 128;
  const int E0   = in_sizes[1] / 2;
  const int Etot = E0 + N;

  float* out_h2 = (float*)d_out;
  float* out_a1 = out_h2 + (size_t)N * 32;
  float* out_a2 = out_a1 + Etot;

  char* wsp = (char*)d_ws; size_t woff = 0;
  auto alloc = [&](size_t bytes)->void*{
    void* p = wsp + woff; woff += (bytes + 255) & ~(size_t)255; return p;
  };
  int*   deg    = (int*)  alloc((size_t)N * 4);
  int*   offs   = (int*)  alloc(((size_t)N + 1) * 4);
  int*   cursor = (int*)  alloc((size_t)N * 4);
  int*   bsums  = (int*)  alloc(4096);
  int*   ssrc   = (int*)  alloc((size_t)Etot * 4);
  float* h1     = (float*)alloc((size_t)N * 64 * 4);
  float* g1     = (float*)alloc((size_t)N * 64 * 4);
  float* h2l    = (float*)alloc((size_t)N * 32 * 4);
  float* s1s    = (float*)alloc((size_t)N * 4);
  float* s1d    = (float*)alloc((size_t)N * 4);
  float* s2s    = (float*)alloc((size_t)N * 4);
  float* s2d    = (float*)alloc((size_t)N * 4);
  float* gm1    = (float*)alloc((size_t)N * 4);
  float* inv1   = (float*)alloc((size_t)N * 4);
  float* gm2    = (float*)alloc((size_t)N * 4);
  float* inv2   = (float*)alloc((size_t)N * 4);

  const int tb = 256;
  hipMemsetAsync(deg, 0, (size_t)N * 4, stream);
  k_hist<<<(Etot + tb - 1) / tb, tb, 0, stream>>>(ei, E0, Etot, deg);
  int nb = (N + 1023) / 1024;
  k_scan1<<<nb, 256, 0, stream>>>(deg, offs, bsums, N);
  k_scan2<<<1, 1024, 0, stream>>>(bsums, nb);
  k_scan3<<<(N + tb - 1) / tb, tb, 0, stream>>>(offs, cursor, bsums, N, Etot);
  k_scatter<<<1024 * 8, 256, 0, stream>>>(ei, E0, Etot, N, cursor, ssrc);

  const int nlb = (N + 255) / 256;
  k_linear<128, 64><<<nlb, 256, 0, stream>>>(x, W1, a_s1, a_d1, h1, s1s, s1d, N);
  k_segment<64, true><<<(N + 3) / 4, 256, 0, stream>>>(offs, ssrc, s1s, s1d, h1, b1, g1, gm1, inv1, N);
  k_linear<64, 32><<<nlb, 256, 0, stream>>>(g1, W2, a_s2, a_d2, h2l, s2s, s2d, N);
  k_segment<32, false><<<(N + 3) / 4, 256, 0, stream>>>(offs, ssrc, s2s, s2d, h2l, b2, out_h2, gm2, inv2, N);
  k_alpha<<<(Etot + tb - 1) / tb, tb, 0, stream>>>(ei, E0, Etot, s1s, s1d, gm1, inv1, s2s, s2d, gm2, inv2, out_a1, out_a2);
}

// Round 5
// 571.436 us; speedup vs baseline: 2.5824x; 1.1831x over previous
//
#include <hip/hip_runtime.h>
#include <float.h>

#define K1E 6528   // edges per k_split block (13KB u32 stage + 4KB counters in LDS)

__device__ __forceinline__ float wredmax(float v){
#pragma unroll
  for (int m = 32; m >= 1; m >>= 1) v = fmaxf(v, __shfl_xor(v, m, 64));
  return v;
}
__device__ __forceinline__ float wredsum(float v){
#pragma unroll
  for (int m = 32; m >= 1; m >>= 1) v += __shfl_xor(v, m, 64);
  return v;
}

// ---------------- CSR build: deterministic two-level counting sort ----------------
// Pass 1: per-block split by bucket (dst>>8), packed u32 = (dst&255)<<17 | src.
// No global atomics anywhere.
__global__ __launch_bounds__(256) void k_split(
    const int* __restrict__ ei, int E0, int total, int NB, int C1,
    unsigned* __restrict__ temp, int* __restrict__ tcounts, int* __restrict__ trunstart)
{
  __shared__ int cnt[512];
  __shared__ int pref[512];
  __shared__ unsigned stage[K1E];
  const int tid = threadIdx.x, blk = blockIdx.x;
  const int lo = blk * K1E, hi = min(lo + K1E, total);

  for (int i = tid; i < 512; i += 256) cnt[i] = 0;
  __syncthreads();
  for (int i = lo + tid; i < hi; i += 256){
    int d = (i < E0) ? ei[E0 + i] : (i - E0);
    atomicAdd(&cnt[d >> 8], 1);
  }
  __syncthreads();
  for (int i = tid; i < 512; i += 256) pref[i] = cnt[i];
  __syncthreads();
  // Hillis-Steele inclusive scan over 512 entries (2 per thread)
  for (int off = 1; off < 512; off <<= 1){
    int a0 = (tid >= off) ? pref[tid - off] : 0;
    int a1 = pref[tid + 256 - off];          // tid+256 >= 256 >= off always
    __syncthreads();
    pref[tid] += a0;
    pref[tid + 256] += a1;
    __syncthreads();
  }
  for (int i = tid; i < NB; i += 256){
    int c = cnt[i];
    int ex = pref[i] - c;                    // exclusive within block
    tcounts[(size_t)i * C1 + blk] = c;
    trunstart[(size_t)i * C1 + blk] = ex;
    cnt[i] = ex;                             // becomes LDS cursor
  }
  __syncthreads();
  for (int i = lo + tid; i < hi; i += 256){
    int s, d;
    if (i < E0){ s = ei[i]; d = ei[E0 + i]; } else { s = i - E0; d = s; }
    int p = atomicAdd(&cnt[d >> 8], 1);      // LDS atomic
    stage[p] = ((unsigned)(d & 255) << 17) | (unsigned)s;
  }
  __syncthreads();
  for (int i = tid; i < hi - lo; i += 256) temp[(size_t)lo + i] = stage[i];
}

// Pass 2: bucket bases = scan of per-bucket totals (single block)
__global__ __launch_bounds__(512) void k_bases(
    const int* __restrict__ tcounts, int NB, int C1, int total,
    int* __restrict__ bases, int* __restrict__ offs, int N)
{
  __shared__ int sc[512];
  const int t = threadIdx.x;
  int s = 0;
  if (t < NB){
    const int* row = tcounts + (size_t)t * C1;
    for (int k = 0; k < C1; ++k) s += row[k];
  }
  sc[t] = s; __syncthreads();
  for (int off = 1; off < 512; off <<= 1){
    int a = (t >= off) ? sc[t - off] : 0;
    __syncthreads();
    sc[t] += a;
    __syncthreads();
  }
  if (t < NB) bases[t] = sc[t] - s;          // exclusive
  if (t == 0) offs[N] = total;
}

// Pass 3: per 256-node bucket, counting-sort by node (LDS atomics), write offs+ssrc
__global__ __launch_bounds__(512) void k_bucket(
    const unsigned* __restrict__ temp, const int* __restrict__ tcounts,
    const int* __restrict__ trunstart, const int* __restrict__ bases,
    int C1, int N, int* __restrict__ ssrc, int* __restrict__ offs)
{
  __shared__ int rloc[1024], rlen[1024];
  __shared__ int cnt[256], sc[256];
  const int b = blockIdx.x, t = threadIdx.x;
  const int bb = bases[b];
  const int node0 = b << 8;
  const int nnode = min(256, N - node0);

  for (int k = t; k < C1; k += 512){
    rlen[k] = tcounts[(size_t)b * C1 + k];
    rloc[k] = k * K1E + trunstart[(size_t)b * C1 + k];
  }
  if (t < 256) cnt[t] = 0;
  __syncthreads();
  for (int r = t; r < C1; r += 512){
    const int L = rlen[r], base = rloc[r];
    for (int q = 0; q < L; ++q) atomicAdd(&cnt[temp[base + q] >> 17], 1);
  }
  __syncthreads();
  if (t < 256) sc[t] = cnt[t];
  __syncthreads();
  for (int off = 1; off < 256; off <<= 1){
    int a = (t < 256 && t >= off) ? sc[t - off] : 0;
    __syncthreads();
    if (t < 256) sc[t] += a;
    __syncthreads();
  }
  if (t < 256){
    int ex = sc[t] - cnt[t];
    if (t < nnode) offs[node0 + t] = bb + ex;
    cnt[t] = ex;                              // cursor
  }
  __syncthreads();
  for (int r = t; r < C1; r += 512){
    const int L = rlen[r], base = rloc[r];
    for (int q = 0; q < L; ++q){
      unsigned v = temp[base + q];
      int p = atomicAdd(&cnt[v >> 17], 1);    // LDS atomic
      ssrc[bb + p] = (int)(v & 0x1FFFFu);
    }
  }
}

// ---------------- fused linear + score kernel ----------------
template<int FIN, int FOUT>
__global__ __launch_bounds__(256) void k_linear(
    const float* __restrict__ x, const float* __restrict__ W,
    const float* __restrict__ a_s, const float* __restrict__ a_d,
    float* __restrict__ h, float* __restrict__ s_src, float* __restrict__ s_dst, int n)
{
  constexpr int CK = 32;
  constexpr int NCH = FIN / CK;
  __shared__ float xs[CK][257];
  const int tid = threadIdx.x;
  const int node0 = blockIdx.x * 256;
  const int node = node0 + tid;
  const int nrow = min(256, n - node0);

  float acc[FOUT];
#pragma unroll
  for (int o = 0; o < FOUT; ++o) acc[o] = 0.f;

  for (int kc = 0; kc < NCH; ++kc){
    __syncthreads();
    const int r0 = tid >> 3;
    const int c4 = tid & 7;
#pragma unroll
    for (int p = 0; p < 8; ++p){
      int row = p * 32 + r0;
      if (row < nrow){
        const float4 v = *reinterpret_cast<const float4*>(
            x + (size_t)(node0 + row) * FIN + kc * CK + c4 * 4);
        xs[c4 * 4 + 0][row] = v.x;
        xs[c4 * 4 + 1][row] = v.y;
        xs[c4 * 4 + 2][row] = v.z;
        xs[c4 * 4 + 3][row] = v.w;
      }
    }
    __syncthreads();
#pragma unroll 8
    for (int k = 0; k < CK; ++k){
      float xv = xs[k][tid];
      const int kg = kc * CK + k;
#pragma unroll
      for (int o4 = 0; o4 < FOUT / 4; ++o4){
        const float4 w = *reinterpret_cast<const float4*>(W + (size_t)kg * FOUT + o4 * 4);
        acc[o4 * 4 + 0] = fmaf(xv, w.x, acc[o4 * 4 + 0]);
        acc[o4 * 4 + 1] = fmaf(xv, w.y, acc[o4 * 4 + 1]);
        acc[o4 * 4 + 2] = fmaf(xv, w.z, acc[o4 * 4 + 2]);
        acc[o4 * 4 + 3] = fmaf(xv, w.w, acc[o4 * 4 + 3]);
      }
    }
  }

  if (node < n){
    float vs = 0.f, vd = 0.f;
#pragma unroll
    for (int o4 = 0; o4 < FOUT / 4; ++o4){
      float4 o;
      o.x = acc[o4 * 4 + 0]; o.y = acc[o4 * 4 + 1];
      o.z = acc[o4 * 4 + 2]; o.w = acc[o4 * 4 + 3];
      *reinterpret_cast<float4*>(h + (size_t)node * FOUT + o4 * 4) = o;
      const float4 as = *reinterpret_cast<const float4*>(a_s + o4 * 4);
      const float4 ad = *reinterpret_cast<const float4*>(a_d + o4 * 4);
      vs += o.x * as.x + o.y * as.y + o.z * as.z + o.w * as.w;
      vd += o.x * ad.x + o.y * ad.y + o.z * ad.z + o.w * ad.w;
    }
    s_src[node] = vs;
    s_dst[node] = vd;
  }
}

// ---------------- segment softmax + aggregate ----------------
template<int F, bool ELU>
__global__ __launch_bounds__(256) void k_segment(
    const int* __restrict__ offs, const int* __restrict__ ssrc,
    const float* __restrict__ s_src, const float* __restrict__ s_dst,
    const float* __restrict__ h, const float* __restrict__ bias,
    float* __restrict__ out, float* __restrict__ gmv, float* __restrict__ invv, int n)
{
  int wid = (blockIdx.x * blockDim.x + threadIdx.x) >> 6;
  if (wid >= n) return;
  int lane = threadIdx.x & 63;
  int beg = offs[wid], end = offs[wid + 1];
  float sd = s_dst[wid];

  float m = -FLT_MAX, ss = 0.f;
  for (int j = beg + lane; j < end; j += 64){
    int s = ssrc[j];
    float e = s_src[s] + sd;
    e = (e > 0.f) ? e : 0.2f * e;
    if (e > m){ ss = ss * __expf(m - e) + 1.f; m = e; }
    else ss += __expf(e - m);
  }
  float gm = wredmax(m);
  float denom = wredsum(ss * __expf(m - gm));
  float inv = 1.f / denom;
  if (lane == 0){ gmv[wid] = gm; invv[wid] = inv; }

  constexpr int FG = F / 4;
  constexpr int ES = 64 / FG;
  int es = lane / FG, fg = lane % FG;
  float ax = 0.f, ay = 0.f, az = 0.f, aw = 0.f;
#pragma unroll 2
  for (int j = beg; j < end; j += ES){
    int jj = j + es;
    if (jj < end){
      int s = ssrc[jj];
      float e = s_src[s] + sd;
      e = (e > 0.f) ? e : 0.2f * e;
      float w = __expf(e - gm) * inv;
      const float4 hv = *reinterpret_cast<const float4*>(h + (size_t)s * F + fg * 4);
      ax = fmaf(w, hv.x, ax); ay = fmaf(w, hv.y, ay);
      az = fmaf(w, hv.z, az); aw = fmaf(w, hv.w, aw);
    }
  }
#pragma unroll
  for (int mm = FG; mm < 64; mm <<= 1){
    ax += __shfl_xor(ax, mm, 64); ay += __shfl_xor(ay, mm, 64);
    az += __shfl_xor(az, mm, 64); aw += __shfl_xor(aw, mm, 64);
  }
  if (lane < FG){
    float4 o;
    o.x = ax + bias[fg * 4 + 0];
    o.y = ay + bias[fg * 4 + 1];
    o.z = az + bias[fg * 4 + 2];
    o.w = aw + bias[fg * 4 + 3];
    if (ELU){
      o.x = (o.x > 0.f) ? o.x : (__expf(o.x) - 1.f);
      o.y = (o.y > 0.f) ? o.y : (__expf(o.y) - 1.f);
      o.z = (o.z > 0.f) ? o.z : (__expf(o.z) - 1.f);
      o.w = (o.w > 0.f) ? o.w : (__expf(o.w) - 1.f);
    }
    *reinterpret_cast<float4*>(out + (size_t)wid * F + fg * 4) = o;
  }
}

// ---------------- alpha in original edge order (coalesced) ----------------
__global__ __launch_bounds__(256) void k_alpha(
    const int* __restrict__ ei, int E0, int total,
    const float* __restrict__ ss1, const float* __restrict__ sd1,
    const float* __restrict__ gm1, const float* __restrict__ inv1,
    const float* __restrict__ ss2, const float* __restrict__ sd2,
    const float* __restrict__ gm2, const float* __restrict__ inv2,
    float* __restrict__ a1, float* __restrict__ a2)
{
  int i = blockIdx.x * blockDim.x + threadIdx.x;
  if (i >= total) return;
  int s, d;
  if (i < E0){ s = ei[i]; d = ei[E0 + i]; } else { s = i - E0; d = s; }
  float e1 = ss1[s] + sd1[d];
  e1 = (e1 > 0.f) ? e1 : 0.2f * e1;
  a1[i] = __expf(e1 - gm1[d]) * inv1[d];
  float e2 = ss2[s] + sd2[d];
  e2 = (e2 > 0.f) ? e2 : 0.2f * e2;
  a2[i] = __expf(e2 - gm2[d]) * inv2[d];
}

// ---------------- launch ----------------
extern "C" void kernel_launch(void* const* d_in, const int* in_sizes, int n_in,
                              void* d_out, int out_size, void* d_ws, size_t ws_size,
                              hipStream_t stream)
{
  const float* x    = (const float*)d_in[0];
  const int*   ei   = (const int*)  d_in[1];
  const float* W1   = (const float*)d_in[2];
  const float* a_s1 = (const float*)d_in[3];
  const float* a_d1 = (const float*)d_in[4];
  const float* b1   = (const float*)d_in[5];
  const float* W2   = (const float*)d_in[6];
  const float* a_s2 = (const float*)d_in[7];
  const float* a_d2 = (const float*)d_in[8];
  const float* b2   = (const float*)d_in[9];

  const int N    = in_sizes[0] / 128;   // 100000 (< 2^17, packing requirement)
  const int E0   = in_sizes[1] / 2;
  const int Etot = E0 + N;
  const int NB   = (N + 255) >> 8;      // 391 buckets (<= 512)
  const int C1   = (Etot + K1E - 1) / K1E;

  float* out_h2 = (float*)d_out;
  float* out_a1 = out_h2 + (size_t)N * 32;
  float* out_a2 = out_a1 + Etot;

  char* wsp = (char*)d_ws; size_t woff = 0;
  auto alloc = [&](size_t bytes)->void*{
    void* p = wsp + woff; woff += (bytes + 255) & ~(size_t)255; return p;
  };
  unsigned* temp     = (unsigned*)alloc((size_t)C1 * K1E * 4);
  int*      tcounts  = (int*)  alloc((size_t)NB * C1 * 4);
  int*      trunstart= (int*)  alloc((size_t)NB * C1 * 4);
  int*      bases    = (int*)  alloc((size_t)(NB + 1) * 4);
  int*      offs     = (int*)  alloc(((size_t)N + 1) * 4);
  int*      ssrc     = (int*)  alloc((size_t)Etot * 4);
  float*    h1       = (float*)alloc((size_t)N * 64 * 4);
  float*    g1       = (float*)alloc((size_t)N * 64 * 4);
  float*    h2l      = (float*)alloc((size_t)N * 32 * 4);
  float*    s1s      = (float*)alloc((size_t)N * 4);
  float*    s1d      = (float*)alloc((size_t)N * 4);
  float*    s2s      = (float*)alloc((size_t)N * 4);
  float*    s2d      = (float*)alloc((size_t)N * 4);
  float*    gm1      = (float*)alloc((size_t)N * 4);
  float*    inv1     = (float*)alloc((size_t)N * 4);
  float*    gm2      = (float*)alloc((size_t)N * 4);
  float*    inv2     = (float*)alloc((size_t)N * 4);

  const int tb = 256;
  k_split<<<C1, 256, 0, stream>>>(ei, E0, Etot, NB, C1, temp, tcounts, trunstart);
  k_bases<<<1, 512, 0, stream>>>(tcounts, NB, C1, Etot, bases, offs, N);
  k_bucket<<<NB, 512, 0, stream>>>(temp, tcounts, trunstart, bases, C1, N, ssrc, offs);

  const int nlb = (N + 255) / 256;
  k_linear<128, 64><<<nlb, 256, 0, stream>>>(x, W1, a_s1, a_d1, h1, s1s, s1d, N);
  k_segment<64, true><<<(N + 3) / 4, 256, 0, stream>>>(offs, ssrc, s1s, s1d, h1, b1, g1, gm1, inv1, N);
  k_linear<64, 32><<<nlb, 256, 0, stream>>>(g1, W2, a_s2, a_d2, h2l, s2s, s2d, N);
  k_segment<32, false><<<(N + 3) / 4, 256, 0, stream>>>(offs, ssrc, s2s, s2d, h2l, b2, out_h2, gm2, inv2, N);
  k_alpha<<<(Etot + tb - 1) / tb, tb, 0, stream>>>(ei, E0, Etot, s1s, s1d, gm1, inv1, s2s, s2d, gm2, inv2, out_a1, out_a2);
}

// Round 6
// 514.256 us; speedup vs baseline: 2.8695x; 1.1112x over previous
//
#include <hip/hip_runtime.h>
#include <hip/hip_fp16.h>
#include <float.h>

#define K1E 6528   // edges per k_split block (13KB u32 stage + 4KB counters in LDS)

__device__ __forceinline__ float wredmax(float v){
#pragma unroll
  for (int m = 32; m >= 1; m >>= 1) v = fmaxf(v, __shfl_xor(v, m, 64));
  return v;
}
__device__ __forceinline__ float wredsum(float v){
#pragma unroll
  for (int m = 32; m >= 1; m >>= 1) v += __shfl_xor(v, m, 64);
  return v;
}
__device__ __forceinline__ unsigned pk2(float a, float b){
  __half2 t = __floats2half2_rn(a, b);
  return __builtin_bit_cast(unsigned, t);
}
__device__ __forceinline__ float2 upk2(unsigned u){
  return __half22float2(__builtin_bit_cast(__half2, u));
}

// ---------------- CSR build: deterministic two-level counting sort ----------------
__global__ __launch_bounds__(256) void k_split(
    const int* __restrict__ ei, int E0, int total, int NB, int C1,
    unsigned* __restrict__ temp, int* __restrict__ tcounts, int* __restrict__ trunstart)
{
  __shared__ int cnt[512];
  __shared__ int pref[512];
  __shared__ unsigned stage[K1E];
  const int tid = threadIdx.x, blk = blockIdx.x;
  const int lo = blk * K1E, hi = min(lo + K1E, total);

  for (int i = tid; i < 512; i += 256) cnt[i] = 0;
  __syncthreads();
  for (int i = lo + tid; i < hi; i += 256){
    int d = (i < E0) ? ei[E0 + i] : (i - E0);
    atomicAdd(&cnt[d >> 8], 1);
  }
  __syncthreads();
  for (int i = tid; i < 512; i += 256) pref[i] = cnt[i];
  __syncthreads();
  for (int off = 1; off < 512; off <<= 1){
    int a0 = (tid >= off) ? pref[tid - off] : 0;
    int a1 = pref[tid + 256 - off];
    __syncthreads();
    pref[tid] += a0;
    pref[tid + 256] += a1;
    __syncthreads();
  }
  for (int i = tid; i < NB; i += 256){
    int c = cnt[i];
    int ex = pref[i] - c;
    tcounts[(size_t)i * C1 + blk] = c;
    trunstart[(size_t)i * C1 + blk] = ex;
    cnt[i] = ex;
  }
  __syncthreads();
  for (int i = lo + tid; i < hi; i += 256){
    int s, d;
    if (i < E0){ s = ei[i]; d = ei[E0 + i]; } else { s = i - E0; d = s; }
    int p = atomicAdd(&cnt[d >> 8], 1);
    stage[p] = ((unsigned)(d & 255) << 17) | (unsigned)s;
  }
  __syncthreads();
  for (int i = tid; i < hi - lo; i += 256) temp[(size_t)lo + i] = stage[i];
}

__global__ __launch_bounds__(512) void k_bases(
    const int* __restrict__ tcounts, int NB, int C1, int total,
    int* __restrict__ bases, int* __restrict__ offs, int N)
{
  __shared__ int sc[512];
  const int t = threadIdx.x;
  int s = 0;
  if (t < NB){
    const int* row = tcounts + (size_t)t * C1;
    for (int k = 0; k < C1; ++k) s += row[k];
  }
  sc[t] = s; __syncthreads();
  for (int off = 1; off < 512; off <<= 1){
    int a = (t >= off) ? sc[t - off] : 0;
    __syncthreads();
    sc[t] += a;
    __syncthreads();
  }
  if (t < NB) bases[t] = sc[t] - s;
  if (t == 0) offs[N] = total;
}

__global__ __launch_bounds__(512) void k_bucket(
    const unsigned* __restrict__ temp, const int* __restrict__ tcounts,
    const int* __restrict__ trunstart, const int* __restrict__ bases,
    int C1, int N, int* __restrict__ ssrc, int* __restrict__ offs)
{
  __shared__ int rloc[1024], rlen[1024];
  __shared__ int cnt[256], sc[256];
  const int b = blockIdx.x, t = threadIdx.x;
  const int bb = bases[b];
  const int node0 = b << 8;
  const int nnode = min(256, N - node0);

  for (int k = t; k < C1; k += 512){
    rlen[k] = tcounts[(size_t)b * C1 + k];
    rloc[k] = k * K1E + trunstart[(size_t)b * C1 + k];
  }
  if (t < 256) cnt[t] = 0;
  __syncthreads();
  for (int r = t; r < C1; r += 512){
    const int L = rlen[r], base = rloc[r];
    for (int q = 0; q < L; ++q) atomicAdd(&cnt[temp[base + q] >> 17], 1);
  }
  __syncthreads();
  if (t < 256) sc[t] = cnt[t];
  __syncthreads();
  for (int off = 1; off < 256; off <<= 1){
    int a = (t < 256 && t >= off) ? sc[t - off] : 0;
    __syncthreads();
    if (t < 256) sc[t] += a;
    __syncthreads();
  }
  if (t < 256){
    int ex = sc[t] - cnt[t];
    if (t < nnode) offs[node0 + t] = bb + ex;
    cnt[t] = ex;
  }
  __syncthreads();
  for (int r = t; r < C1; r += 512){
    const int L = rlen[r], base = rloc[r];
    for (int q = 0; q < L; ++q){
      unsigned v = temp[base + q];
      int p = atomicAdd(&cnt[v >> 17], 1);
      ssrc[bb + p] = (int)(v & 0x1FFFFu);
    }
  }
}

// ---------------- fused linear + score kernel (fp16 h output) ----------------
template<int FIN, int FOUT>
__global__ __launch_bounds__(256) void k_linear(
    const float* __restrict__ x, const float* __restrict__ W,
    const float* __restrict__ a_s, const float* __restrict__ a_d,
    __half* __restrict__ h16, float* __restrict__ s_src, float* __restrict__ s_dst, int n)
{
  constexpr int CK = 32;
  constexpr int NCH = FIN / CK;
  __shared__ float xs[CK][257];
  const int tid = threadIdx.x;
  const int node0 = blockIdx.x * 256;
  const int node = node0 + tid;
  const int nrow = min(256, n - node0);

  float acc[FOUT];
#pragma unroll
  for (int o = 0; o < FOUT; ++o) acc[o] = 0.f;

  for (int kc = 0; kc < NCH; ++kc){
    __syncthreads();
    const int r0 = tid >> 3;
    const int c4 = tid & 7;
#pragma unroll
    for (int p = 0; p < 8; ++p){
      int row = p * 32 + r0;
      if (row < nrow){
        const float4 v = *reinterpret_cast<const float4*>(
            x + (size_t)(node0 + row) * FIN + kc * CK + c4 * 4);
        xs[c4 * 4 + 0][row] = v.x;
        xs[c4 * 4 + 1][row] = v.y;
        xs[c4 * 4 + 2][row] = v.z;
        xs[c4 * 4 + 3][row] = v.w;
      }
    }
    __syncthreads();
#pragma unroll 8
    for (int k = 0; k < CK; ++k){
      float xv = xs[k][tid];
      const int kg = kc * CK + k;
#pragma unroll
      for (int o4 = 0; o4 < FOUT / 4; ++o4){
        const float4 w = *reinterpret_cast<const float4*>(W + (size_t)kg * FOUT + o4 * 4);
        acc[o4 * 4 + 0] = fmaf(xv, w.x, acc[o4 * 4 + 0]);
        acc[o4 * 4 + 1] = fmaf(xv, w.y, acc[o4 * 4 + 1]);
        acc[o4 * 4 + 2] = fmaf(xv, w.z, acc[o4 * 4 + 2]);
        acc[o4 * 4 + 3] = fmaf(xv, w.w, acc[o4 * 4 + 3]);
      }
    }
  }

  if (node < n){
    float vs = 0.f, vd = 0.f;
#pragma unroll
    for (int o4 = 0; o4 < FOUT / 4; ++o4){
      const float4 as = *reinterpret_cast<const float4*>(a_s + o4 * 4);
      const float4 ad = *reinterpret_cast<const float4*>(a_d + o4 * 4);
      vs += acc[o4*4+0]*as.x + acc[o4*4+1]*as.y + acc[o4*4+2]*as.z + acc[o4*4+3]*as.w;
      vd += acc[o4*4+0]*ad.x + acc[o4*4+1]*ad.y + acc[o4*4+2]*ad.z + acc[o4*4+3]*ad.w;
    }
#pragma unroll
    for (int c = 0; c < FOUT / 8; ++c){
      uint4 u;
      u.x = pk2(acc[c*8+0], acc[c*8+1]);
      u.y = pk2(acc[c*8+2], acc[c*8+3]);
      u.z = pk2(acc[c*8+4], acc[c*8+5]);
      u.w = pk2(acc[c*8+6], acc[c*8+7]);
      *reinterpret_cast<uint4*>(h16 + (size_t)node * FOUT + c * 8) = u;
    }
    s_src[node] = vs;
    s_dst[node] = vd;
  }
}

// ---------------- segment softmax + aggregate (fp16 h gather) ----------------
template<int F, bool ELU>
__global__ __launch_bounds__(256) void k_segment(
    const int* __restrict__ offs, const int* __restrict__ ssrc,
    const float* __restrict__ s_src, const float* __restrict__ s_dst,
    const __half* __restrict__ h16, const float* __restrict__ bias,
    float* __restrict__ out, float* __restrict__ gmv, float* __restrict__ invv, int n)
{
  int wid = (blockIdx.x * blockDim.x + threadIdx.x) >> 6;
  if (wid >= n) return;
  int lane = threadIdx.x & 63;
  int beg = offs[wid], end = offs[wid + 1];
  float sd = s_dst[wid];

  // pass A: online (max, scaled-sum), lanes strided over edges
  float m = -FLT_MAX, ss = 0.f;
  for (int j = beg + lane; j < end; j += 64){
    int s = ssrc[j];
    float e = s_src[s] + sd;
    e = (e > 0.f) ? e : 0.2f * e;
    if (e > m){ ss = ss * __expf(m - e) + 1.f; m = e; }
    else ss += __expf(e - m);
  }
  float gm = wredmax(m);
  float denom = wredsum(ss * __expf(m - gm));
  float inv = 1.f / denom;
  if (lane == 0){ gmv[wid] = gm; invv[wid] = inv; }

  // pass B: FG lanes per edge (uint4 = 8 halves each), ES edges in flight
  constexpr int FG = F / 8;      // lanes per edge (F=64 -> 8, F=32 -> 4)
  constexpr int ES = 64 / FG;    // edge slots    (F=64 -> 8, F=32 -> 16)
  int es = lane / FG, fg = lane % FG;
  float a0=0.f,a1=0.f,a2=0.f,a3=0.f,a4=0.f,a5=0.f,a6=0.f,a7=0.f;
  for (int j = beg; j < end; j += ES){
    int jj = j + es;
    if (jj < end){
      int s = ssrc[jj];
      float e = s_src[s] + sd;
      e = (e > 0.f) ? e : 0.2f * e;
      float w = __expf(e - gm) * inv;
      const uint4 hv = *reinterpret_cast<const uint4*>(h16 + (size_t)s * F + fg * 8);
      float2 f0 = upk2(hv.x), f1 = upk2(hv.y), f2 = upk2(hv.z), f3 = upk2(hv.w);
      a0 = fmaf(w, f0.x, a0); a1 = fmaf(w, f0.y, a1);
      a2 = fmaf(w, f1.x, a2); a3 = fmaf(w, f1.y, a3);
      a4 = fmaf(w, f2.x, a4); a5 = fmaf(w, f2.y, a5);
      a6 = fmaf(w, f3.x, a6); a7 = fmaf(w, f3.y, a7);
    }
  }
#pragma unroll
  for (int mm = FG; mm < 64; mm <<= 1){
    a0 += __shfl_xor(a0, mm, 64); a1 += __shfl_xor(a1, mm, 64);
    a2 += __shfl_xor(a2, mm, 64); a3 += __shfl_xor(a3, mm, 64);
    a4 += __shfl_xor(a4, mm, 64); a5 += __shfl_xor(a5, mm, 64);
    a6 += __shfl_xor(a6, mm, 64); a7 += __shfl_xor(a7, mm, 64);
  }
  if (lane < FG){
    float o[8] = {a0,a1,a2,a3,a4,a5,a6,a7};
#pragma unroll
    for (int q = 0; q < 8; ++q){
      float v = o[q] + bias[fg * 8 + q];
      if (ELU) v = (v > 0.f) ? v : (__expf(v) - 1.f);
      o[q] = v;
    }
    float4 w0 = {o[0],o[1],o[2],o[3]}, w1 = {o[4],o[5],o[6],o[7]};
    *reinterpret_cast<float4*>(out + (size_t)wid * F + fg * 8)     = w0;
    *reinterpret_cast<float4*>(out + (size_t)wid * F + fg * 8 + 4) = w1;
  }
}

// ---------------- alpha in original edge order (coalesced) ----------------
__global__ __launch_bounds__(256) void k_alpha(
    const int* __restrict__ ei, int E0, int total,
    const float* __restrict__ ss1, const float* __restrict__ sd1,
    const float* __restrict__ gm1, const float* __restrict__ inv1,
    const float* __restrict__ ss2, const float* __restrict__ sd2,
    const float* __restrict__ gm2, const float* __restrict__ inv2,
    float* __restrict__ a1, float* __restrict__ a2)
{
  int i = blockIdx.x * blockDim.x + threadIdx.x;
  if (i >= total) return;
  int s, d;
  if (i < E0){ s = ei[i]; d = ei[E0 + i]; } else { s = i - E0; d = s; }
  float e1 = ss1[s] + sd1[d];
  e1 = (e1 > 0.f) ? e1 : 0.2f * e1;
  a1[i] = __expf(e1 - gm1[d]) * inv1[d];
  float e2 = ss2[s] + sd2[d];
  e2 = (e2 > 0.f) ? e2 : 0.2f * e2;
  a2[i] = __expf(e2 - gm2[d]) * inv2[d];
}

// ---------------- launch ----------------
extern "C" void kernel_launch(void* const* d_in, const int* in_sizes, int n_in,
                              void* d_out, int out_size, void* d_ws, size_t ws_size,
                              hipStream_t stream)
{
  const float* x    = (const float*)d_in[0];
  const int*   ei   = (const int*)  d_in[1];
  const float* W1   = (const float*)d_in[2];
  const float* a_s1 = (const float*)d_in[3];
  const float* a_d1 = (const float*)d_in[4];
  const float* b1   = (const float*)d_in[5];
  const float* W2   = (const float*)d_in[6];
  const float* a_s2 = (const float*)d_in[7];
  const float* a_d2 = (const float*)d_in[8];
  const float* b2   = (const float*)d_in[9];

  const int N    = in_sizes[0] / 128;   // 100000 (< 2^17, packing requirement)
  const int E0   = in_sizes[1] / 2;
  const int Etot = E0 + N;
  const int NB   = (N + 255) >> 8;      // 391 buckets
  const int C1   = (Etot + K1E - 1) / K1E;

  float* out_h2 = (float*)d_out;
  float* out_a1 = out_h2 + (size_t)N * 32;
  float* out_a2 = out_a1 + Etot;

  char* wsp = (char*)d_ws; size_t woff = 0;
  auto alloc = [&](size_t bytes)->void*{
    void* p = wsp + woff; woff += (bytes + 255) & ~(size_t)255; return p;
  };
  unsigned* temp     = (unsigned*)alloc((size_t)C1 * K1E * 4);
  int*      tcounts  = (int*)  alloc((size_t)NB * C1 * 4);
  int*      trunstart= (int*)  alloc((size_t)NB * C1 * 4);
  int*      bases    = (int*)  alloc((size_t)(NB + 1) * 4);
  int*      offs     = (int*)  alloc(((size_t)N + 1) * 4);
  int*      ssrc     = (int*)  alloc((size_t)Etot * 4);
  __half*   h1       = (__half*)alloc((size_t)N * 64 * 2);
  float*    g1       = (float*)alloc((size_t)N * 64 * 4);
  __half*   h2l      = (__half*)alloc((size_t)N * 32 * 2);
  float*    s1s      = (float*)alloc((size_t)N * 4);
  float*    s1d      = (float*)alloc((size_t)N * 4);
  float*    s2s      = (float*)alloc((size_t)N * 4);
  float*    s2d      = (float*)alloc((size_t)N * 4);
  float*    gm1      = (float*)alloc((size_t)N * 4);
  float*    inv1     = (float*)alloc((size_t)N * 4);
  float*    gm2      = (float*)alloc((size_t)N * 4);
  float*    inv2     = (float*)alloc((size_t)N * 4);

  const int tb = 256;
  k_split<<<C1, 256, 0, stream>>>(ei, E0, Etot, NB, C1, temp, tcounts, trunstart);
  k_bases<<<1, 512, 0, stream>>>(tcounts, NB, C1, Etot, bases, offs, N);
  k_bucket<<<NB, 512, 0, stream>>>(temp, tcounts, trunstart, bases, C1, N, ssrc, offs);

  const int nlb = (N + 255) / 256;
  k_linear<128, 64><<<nlb, 256, 0, stream>>>(x, W1, a_s1, a_d1, h1, s1s, s1d, N);
  k_segment<64, true><<<(N + 3) / 4, 256, 0, stream>>>(offs, ssrc, s1s, s1d, h1, b1, g1, gm1, inv1, N);
  k_linear<64, 32><<<nlb, 256, 0, stream>>>(g1, W2, a_s2, a_d2, h2l, s2s, s2d, N);
  k_segment<32, false><<<(N + 3) / 4, 256, 0, stream>>>(offs, ssrc, s2s, s2d, h2l, b2, out_h2, gm2, inv2, N);
  k_alpha<<<(Etot + tb - 1) / tb, tb, 0, stream>>>(ei, E0, Etot, s1s, s1d, gm1, inv1, s2s, s2d, gm2, inv2, out_a1, out_a2);
}

// Round 7
// 457.271 us; speedup vs baseline: 3.2271x; 1.1246x over previous
//
#include <hip/hip_runtime.h>
#include <hip/hip_fp16.h>
#include <float.h>

#define K1E 6528   // edges per k_split block (13KB u32 stage + 4KB counters in LDS)

__device__ __forceinline__ float wredmax(float v){
#pragma unroll
  for (int m = 32; m >= 1; m >>= 1) v = fmaxf(v, __shfl_xor(v, m, 64));
  return v;
}
__device__ __forceinline__ float wredsum(float v){
#pragma unroll
  for (int m = 32; m >= 1; m >>= 1) v += __shfl_xor(v, m, 64);
  return v;
}
__device__ __forceinline__ unsigned pk2(float a, float b){
  __half2 t = __floats2half2_rn(a, b);
  return __builtin_bit_cast(unsigned, t);
}
__device__ __forceinline__ float2 upk2(unsigned u){
  return __half22float2(__builtin_bit_cast(__half2, u));
}

// ---------------- CSR build: deterministic two-level counting sort ----------------
__global__ __launch_bounds__(256) void k_split(
    const int* __restrict__ ei, int E0, int total, int NB, int C1,
    unsigned* __restrict__ temp, int* __restrict__ tcounts, int* __restrict__ trunstart)
{
  __shared__ int cnt[512];
  __shared__ int pref[512];
  __shared__ unsigned stage[K1E];
  const int tid = threadIdx.x, blk = blockIdx.x;
  const int lo = blk * K1E, hi = min(lo + K1E, total);

  for (int i = tid; i < 512; i += 256) cnt[i] = 0;
  __syncthreads();
  for (int i = lo + tid; i < hi; i += 256){
    int d = (i < E0) ? ei[E0 + i] : (i - E0);
    atomicAdd(&cnt[d >> 8], 1);
  }
  __syncthreads();
  for (int i = tid; i < 512; i += 256) pref[i] = cnt[i];
  __syncthreads();
  for (int off = 1; off < 512; off <<= 1){
    int a0 = (tid >= off) ? pref[tid - off] : 0;
    int a1 = pref[tid + 256 - off];
    __syncthreads();
    pref[tid] += a0;
    pref[tid + 256] += a1;
    __syncthreads();
  }
  for (int i = tid; i < NB; i += 256){
    int c = cnt[i];
    int ex = pref[i] - c;
    tcounts[(size_t)i * C1 + blk] = c;
    trunstart[(size_t)i * C1 + blk] = ex;
    cnt[i] = ex;
  }
  __syncthreads();
  for (int i = lo + tid; i < hi; i += 256){
    int s, d;
    if (i < E0){ s = ei[i]; d = ei[E0 + i]; } else { s = i - E0; d = s; }
    int p = atomicAdd(&cnt[d >> 8], 1);
    stage[p] = ((unsigned)(d & 255) << 17) | (unsigned)s;
  }
  __syncthreads();
  for (int i = tid; i < hi - lo; i += 256) temp[(size_t)lo + i] = stage[i];
}

__global__ __launch_bounds__(512) void k_bases(
    const int* __restrict__ tcounts, int NB, int C1, int total,
    int* __restrict__ bases, int* __restrict__ offs, int N)
{
  __shared__ int sc[512];
  const int t = threadIdx.x;
  int s = 0;
  if (t < NB){
    const int* row = tcounts + (size_t)t * C1;
    for (int k = 0; k < C1; ++k) s += row[k];
  }
  sc[t] = s; __syncthreads();
  for (int off = 1; off < 512; off <<= 1){
    int a = (t >= off) ? sc[t - off] : 0;
    __syncthreads();
    sc[t] += a;
    __syncthreads();
  }
  if (t < NB) bases[t] = sc[t] - s;
  if (t == 0) offs[N] = total;
}

__global__ __launch_bounds__(512) void k_bucket(
    const unsigned* __restrict__ temp, const int* __restrict__ tcounts,
    const int* __restrict__ trunstart, const int* __restrict__ bases,
    int C1, int N, int* __restrict__ ssrc, int* __restrict__ offs)
{
  __shared__ int rloc[1024], rlen[1024];
  __shared__ int cnt[256], sc[256];
  const int b = blockIdx.x, t = threadIdx.x;
  const int bb = bases[b];
  const int node0 = b << 8;
  const int nnode = min(256, N - node0);

  for (int k = t; k < C1; k += 512){
    rlen[k] = tcounts[(size_t)b * C1 + k];
    rloc[k] = k * K1E + trunstart[(size_t)b * C1 + k];
  }
  if (t < 256) cnt[t] = 0;
  __syncthreads();
  for (int r = t; r < C1; r += 512){
    const int L = rlen[r], base = rloc[r];
    for (int q = 0; q < L; ++q) atomicAdd(&cnt[temp[base + q] >> 17], 1);
  }
  __syncthreads();
  if (t < 256) sc[t] = cnt[t];
  __syncthreads();
  for (int off = 1; off < 256; off <<= 1){
    int a = (t < 256 && t >= off) ? sc[t - off] : 0;
    __syncthreads();
    if (t < 256) sc[t] += a;
    __syncthreads();
  }
  if (t < 256){
    int ex = sc[t] - cnt[t];
    if (t < nnode) offs[node0 + t] = bb + ex;
    cnt[t] = ex;
  }
  __syncthreads();
  for (int r = t; r < C1; r += 512){
    const int L = rlen[r], base = rloc[r];
    for (int q = 0; q < L; ++q){
      unsigned v = temp[base + q];
      int p = atomicAdd(&cnt[v >> 17], 1);
      ssrc[bb + p] = (int)(v & 0x1FFFFu);
    }
  }
}

// ---------------- fused linear + score kernel (fp16 h output) ----------------
template<int FIN, int FOUT>
__global__ __launch_bounds__(256) void k_linear(
    const float* __restrict__ x, const float* __restrict__ W,
    const float* __restrict__ a_s, const float* __restrict__ a_d,
    __half* __restrict__ h16, float* __restrict__ s_src, float* __restrict__ s_dst, int n)
{
  constexpr int CK = 32;
  constexpr int NCH = FIN / CK;
  __shared__ float xs[CK][257];
  const int tid = threadIdx.x;
  const int node0 = blockIdx.x * 256;
  const int node = node0 + tid;
  const int nrow = min(256, n - node0);

  float acc[FOUT];
#pragma unroll
  for (int o = 0; o < FOUT; ++o) acc[o] = 0.f;

  for (int kc = 0; kc < NCH; ++kc){
    __syncthreads();
    const int r0 = tid >> 3;
    const int c4 = tid & 7;
#pragma unroll
    for (int p = 0; p < 8; ++p){
      int row = p * 32 + r0;
      if (row < nrow){
        const float4 v = *reinterpret_cast<const float4*>(
            x + (size_t)(node0 + row) * FIN + kc * CK + c4 * 4);
        xs[c4 * 4 + 0][row] = v.x;
        xs[c4 * 4 + 1][row] = v.y;
        xs[c4 * 4 + 2][row] = v.z;
        xs[c4 * 4 + 3][row] = v.w;
      }
    }
    __syncthreads();
#pragma unroll 8
    for (int k = 0; k < CK; ++k){
      float xv = xs[k][tid];
      const int kg = kc * CK + k;
#pragma unroll
      for (int o4 = 0; o4 < FOUT / 4; ++o4){
        const float4 w = *reinterpret_cast<const float4*>(W + (size_t)kg * FOUT + o4 * 4);
        acc[o4 * 4 + 0] = fmaf(xv, w.x, acc[o4 * 4 + 0]);
        acc[o4 * 4 + 1] = fmaf(xv, w.y, acc[o4 * 4 + 1]);
        acc[o4 * 4 + 2] = fmaf(xv, w.z, acc[o4 * 4 + 2]);
        acc[o4 * 4 + 3] = fmaf(xv, w.w, acc[o4 * 4 + 3]);
      }
    }
  }

  if (node < n){
    float vs = 0.f, vd = 0.f;
#pragma unroll
    for (int o4 = 0; o4 < FOUT / 4; ++o4){
      const float4 as = *reinterpret_cast<const float4*>(a_s + o4 * 4);
      const float4 ad = *reinterpret_cast<const float4*>(a_d + o4 * 4);
      vs += acc[o4*4+0]*as.x + acc[o4*4+1]*as.y + acc[o4*4+2]*as.z + acc[o4*4+3]*as.w;
      vd += acc[o4*4+0]*ad.x + acc[o4*4+1]*ad.y + acc[o4*4+2]*ad.z + acc[o4*4+3]*ad.w;
    }
#pragma unroll
    for (int c = 0; c < FOUT / 8; ++c){
      uint4 u;
      u.x = pk2(acc[c*8+0], acc[c*8+1]);
      u.y = pk2(acc[c*8+2], acc[c*8+3]);
      u.z = pk2(acc[c*8+4], acc[c*8+5]);
      u.w = pk2(acc[c*8+6], acc[c*8+7]);
      *reinterpret_cast<uint4*>(h16 + (size_t)node * FOUT + c * 8) = u;
    }
    s_src[node] = vs;
    s_dst[node] = vd;
  }
}

// ---------------- segment softmax + aggregate (fp16 h gather) ----------------
template<int F, bool ELU>
__global__ __launch_bounds__(256) void k_segment(
    const int* __restrict__ offs, const int* __restrict__ ssrc,
    const float* __restrict__ s_src, const float* __restrict__ s_dst,
    const __half* __restrict__ h16, const float* __restrict__ bias,
    float* __restrict__ out, float* __restrict__ gmv, float* __restrict__ invv, int n)
{
  int wid = (blockIdx.x * blockDim.x + threadIdx.x) >> 6;
  if (wid >= n) return;
  int lane = threadIdx.x & 63;
  int beg = offs[wid], end = offs[wid + 1];
  float sd = s_dst[wid];

  float m = -FLT_MAX, ss = 0.f;
  for (int j = beg + lane; j < end; j += 64){
    int s = ssrc[j];
    float e = s_src[s] + sd;
    e = (e > 0.f) ? e : 0.2f * e;
    if (e > m){ ss = ss * __expf(m - e) + 1.f; m = e; }
    else ss += __expf(e - m);
  }
  float gm = wredmax(m);
  float denom = wredsum(ss * __expf(m - gm));
  float inv = 1.f / denom;
  if (lane == 0){ gmv[wid] = gm; invv[wid] = inv; }

  constexpr int FG = F / 8;
  constexpr int ES = 64 / FG;
  int es = lane / FG, fg = lane % FG;
  float a0=0.f,a1=0.f,a2=0.f,a3=0.f,a4=0.f,a5=0.f,a6=0.f,a7=0.f;
  for (int j = beg; j < end; j += ES){
    int jj = j + es;
    if (jj < end){
      int s = ssrc[jj];
      float e = s_src[s] + sd;
      e = (e > 0.f) ? e : 0.2f * e;
      float w = __expf(e - gm) * inv;
      const uint4 hv = *reinterpret_cast<const uint4*>(h16 + (size_t)s * F + fg * 8);
      float2 f0 = upk2(hv.x), f1 = upk2(hv.y), f2 = upk2(hv.z), f3 = upk2(hv.w);
      a0 = fmaf(w, f0.x, a0); a1 = fmaf(w, f0.y, a1);
      a2 = fmaf(w, f1.x, a2); a3 = fmaf(w, f1.y, a3);
      a4 = fmaf(w, f2.x, a4); a5 = fmaf(w, f2.y, a5);
      a6 = fmaf(w, f3.x, a6); a7 = fmaf(w, f3.y, a7);
    }
  }
#pragma unroll
  for (int mm = FG; mm < 64; mm <<= 1){
    a0 += __shfl_xor(a0, mm, 64); a1 += __shfl_xor(a1, mm, 64);
    a2 += __shfl_xor(a2, mm, 64); a3 += __shfl_xor(a3, mm, 64);
    a4 += __shfl_xor(a4, mm, 64); a5 += __shfl_xor(a5, mm, 64);
    a6 += __shfl_xor(a6, mm, 64); a7 += __shfl_xor(a7, mm, 64);
  }
  if (lane < FG){
    float o[8] = {a0,a1,a2,a3,a4,a5,a6,a7};
#pragma unroll
    for (int q = 0; q < 8; ++q){
      float v = o[q] + bias[fg * 8 + q];
      if (ELU) v = (v > 0.f) ? v : (__expf(v) - 1.f);
      o[q] = v;
    }
    float4 w0 = {o[0],o[1],o[2],o[3]}, w1 = {o[4],o[5],o[6],o[7]};
    *reinterpret_cast<float4*>(out + (size_t)wid * F + fg * 8)     = w0;
    *reinterpret_cast<float4*>(out + (size_t)wid * F + fg * 8 + 4) = w1;
  }
}

// ---------------- pack per-node softmax state (coalesced) ----------------
__global__ __launch_bounds__(256) void k_pack(
    const float* __restrict__ ss1, const float* __restrict__ sd1,
    const float* __restrict__ gm1, const float* __restrict__ inv1,
    const float* __restrict__ ss2, const float* __restrict__ sd2,
    const float* __restrict__ gm2, const float* __restrict__ inv2,
    float2* __restrict__ ssp, float4* __restrict__ pkd, int N)
{
  int i = blockIdx.x * blockDim.x + threadIdx.x;
  if (i >= N) return;
  ssp[i] = make_float2(ss1[i], ss2[i]);
  pkd[2 * i]     = make_float4(sd1[i], gm1[i], inv1[i], sd2[i]);
  pkd[2 * i + 1] = make_float4(gm2[i], inv2[i], 0.f, 0.f);
}

// ---------------- alpha in original edge order (4 edges/thread ILP) ----------------
__global__ __launch_bounds__(256) void k_alpha(
    const int* __restrict__ ei, int E0, int total, int G,
    const float2* __restrict__ ssp, const float4* __restrict__ pkd,
    float* __restrict__ a1, float* __restrict__ a2)
{
  const int t = blockIdx.x * blockDim.x + threadIdx.x;
  int sv[4], dv[4];
  bool ok[4];
#pragma unroll
  for (int q = 0; q < 4; ++q){
    int i = t + q * G;
    ok[q] = i < total;
    if (ok[q]){
      if (i < E0){ sv[q] = ei[i]; dv[q] = ei[E0 + i]; }
      else { sv[q] = i - E0; dv[q] = sv[q]; }
    }
  }
  float2 ssv[4]; float4 da[4], db[4];
#pragma unroll
  for (int q = 0; q < 4; ++q){
    if (ok[q]){
      ssv[q] = ssp[sv[q]];
      da[q]  = pkd[2 * dv[q]];
      db[q]  = pkd[2 * dv[q] + 1];
    }
  }
#pragma unroll
  for (int q = 0; q < 4; ++q){
    if (ok[q]){
      int i = t + q * G;
      float e1 = ssv[q].x + da[q].x;
      e1 = (e1 > 0.f) ? e1 : 0.2f * e1;
      a1[i] = __expf(e1 - da[q].y) * da[q].z;
      float e2 = ssv[q].y + da[q].w;
      e2 = (e2 > 0.f) ? e2 : 0.2f * e2;
      a2[i] = __expf(e2 - db[q].x) * db[q].y;
    }
  }
}

// ---------------- launch ----------------
extern "C" void kernel_launch(void* const* d_in, const int* in_sizes, int n_in,
                              void* d_out, int out_size, void* d_ws, size_t ws_size,
                              hipStream_t stream)
{
  const float* x    = (const float*)d_in[0];
  const int*   ei   = (const int*)  d_in[1];
  const float* W1   = (const float*)d_in[2];
  const float* a_s1 = (const float*)d_in[3];
  const float* a_d1 = (const float*)d_in[4];
  const float* b1   = (const float*)d_in[5];
  const float* W2   = (const float*)d_in[6];
  const float* a_s2 = (const float*)d_in[7];
  const float* a_d2 = (const float*)d_in[8];
  const float* b2   = (const float*)d_in[9];

  const int N    = in_sizes[0] / 128;   // 100000 (< 2^17, packing requirement)
  const int E0   = in_sizes[1] / 2;
  const int Etot = E0 + N;
  const int NB   = (N + 255) >> 8;      // 391 buckets
  const int C1   = (Etot + K1E - 1) / K1E;

  float* out_h2 = (float*)d_out;
  float* out_a1 = out_h2 + (size_t)N * 32;
  float* out_a2 = out_a1 + Etot;

  char* wsp = (char*)d_ws; size_t woff = 0;
  auto alloc = [&](size_t bytes)->void*{
    void* p = wsp + woff; woff += (bytes + 255) & ~(size_t)255; return p;
  };
  unsigned* temp     = (unsigned*)alloc((size_t)C1 * K1E * 4);
  int*      tcounts  = (int*)  alloc((size_t)NB * C1 * 4);
  int*      trunstart= (int*)  alloc((size_t)NB * C1 * 4);
  int*      bases    = (int*)  alloc((size_t)(NB + 1) * 4);
  int*      offs     = (int*)  alloc(((size_t)N + 1) * 4);
  int*      ssrc     = (int*)  alloc((size_t)Etot * 4);
  __half*   h1       = (__half*)alloc((size_t)N * 64 * 2);
  float*    g1       = (float*)alloc((size_t)N * 64 * 4);
  __half*   h2l      = (__half*)alloc((size_t)N * 32 * 2);
  float*    s1s      = (float*)alloc((size_t)N * 4);
  float*    s1d      = (float*)alloc((size_t)N * 4);
  float*    s2s      = (float*)alloc((size_t)N * 4);
  float*    s2d      = (float*)alloc((size_t)N * 4);
  float*    gm1      = (float*)alloc((size_t)N * 4);
  float*    inv1     = (float*)alloc((size_t)N * 4);
  float*    gm2      = (float*)alloc((size_t)N * 4);
  float*    inv2     = (float*)alloc((size_t)N * 4);
  float2*   ssp      = (float2*)alloc((size_t)N * 8);
  float4*   pkd      = (float4*)alloc((size_t)N * 32);

  const int tb = 256;
  k_split<<<C1, 256, 0, stream>>>(ei, E0, Etot, NB, C1, temp, tcounts, trunstart);
  k_bases<<<1, 512, 0, stream>>>(tcounts, NB, C1, Etot, bases, offs, N);
  k_bucket<<<NB, 512, 0, stream>>>(temp, tcounts, trunstart, bases, C1, N, ssrc, offs);

  const int nlb = (N + 255) / 256;
  k_linear<128, 64><<<nlb, 256, 0, stream>>>(x, W1, a_s1, a_d1, h1, s1s, s1d, N);
  k_segment<64, true><<<(N + 3) / 4, 256, 0, stream>>>(offs, ssrc, s1s, s1d, h1, b1, g1, gm1, inv1, N);
  k_linear<64, 32><<<nlb, 256, 0, stream>>>(g1, W2, a_s2, a_d2, h2l, s2s, s2d, N);
  k_segment<32, false><<<(N + 3) / 4, 256, 0, stream>>>(offs, ssrc, s2s, s2d, h2l, b2, out_h2, gm2, inv2, N);

  k_pack<<<nlb, 256, 0, stream>>>(s1s, s1d, gm1, inv1, s2s, s2d, gm2, inv2, ssp, pkd, N);
  const int G = (Etot + 3) / 4;
  k_alpha<<<(G + tb - 1) / tb, tb, 0, stream>>>(ei, E0, Etot, G, ssp, pkd, out_a1, out_a2);
}

// Round 8
// 367.366 us; speedup vs baseline: 4.0169x; 1.2447x over previous
//
#include <hip/hip_runtime.h>
#include <hip/hip_fp16.h>
#include <float.h>

#define K1E 6528   // edges per k_split block (13KB u32 stage + 4KB counters in LDS)

__device__ __forceinline__ float wredmax(float v){
#pragma unroll
  for (int m = 32; m >= 1; m >>= 1) v = fmaxf(v, __shfl_xor(v, m, 64));
  return v;
}
__device__ __forceinline__ float wredsum(float v){
#pragma unroll
  for (int m = 32; m >= 1; m >>= 1) v += __shfl_xor(v, m, 64);
  return v;
}
__device__ __forceinline__ int wredsumi(int v){
#pragma unroll
  for (int m = 32; m >= 1; m >>= 1) v += __shfl_xor(v, m, 64);
  return v;
}
__device__ __forceinline__ unsigned pk2(float a, float b){
  __half2 t = __floats2half2_rn(a, b);
  return __builtin_bit_cast(unsigned, t);
}
__device__ __forceinline__ float2 upk2(unsigned u){
  return __half22float2(__builtin_bit_cast(__half2, u));
}

// ---------------- CSR build: deterministic two-level counting sort ----------------
__global__ __launch_bounds__(256) void k_split(
    const int* __restrict__ ei, int E0, int total, int NB, int C1,
    unsigned* __restrict__ temp, int* __restrict__ tcounts, int* __restrict__ trunstart)
{
  __shared__ int cnt[512];
  __shared__ int pref[512];
  __shared__ unsigned stage[K1E];
  const int tid = threadIdx.x, blk = blockIdx.x;
  const int lo = blk * K1E, hi = min(lo + K1E, total);

  for (int i = tid; i < 512; i += 256) cnt[i] = 0;
  __syncthreads();
  for (int i = lo + tid; i < hi; i += 256){
    int d = (i < E0) ? ei[E0 + i] : (i - E0);
    atomicAdd(&cnt[d >> 8], 1);
  }
  __syncthreads();
  for (int i = tid; i < 512; i += 256) pref[i] = cnt[i];
  __syncthreads();
  for (int off = 1; off < 512; off <<= 1){
    int a0 = (tid >= off) ? pref[tid - off] : 0;
    int a1 = pref[tid + 256 - off];
    __syncthreads();
    pref[tid] += a0;
    pref[tid + 256] += a1;
    __syncthreads();
  }
  for (int i = tid; i < NB; i += 256){
    int c = cnt[i];
    int ex = pref[i] - c;
    tcounts[(size_t)i * C1 + blk] = c;
    trunstart[(size_t)i * C1 + blk] = ex;
    cnt[i] = ex;
  }
  __syncthreads();
  for (int i = lo + tid; i < hi; i += 256){
    int s, d;
    if (i < E0){ s = ei[i]; d = ei[E0 + i]; } else { s = i - E0; d = s; }
    int p = atomicAdd(&cnt[d >> 8], 1);
    stage[p] = ((unsigned)(d & 255) << 17) | (unsigned)s;
  }
  __syncthreads();
  for (int i = tid; i < hi - lo; i += 256) temp[(size_t)lo + i] = stage[i];
}

// per-bucket totals: one block per bucket, coalesced row sum
__global__ __launch_bounds__(256) void k_rowsum(
    const int* __restrict__ tcounts, int C1, int* __restrict__ totals)
{
  const int b = blockIdx.x;
  const int* row = tcounts + (size_t)b * C1;
  int s = 0;
  for (int k = threadIdx.x; k < C1; k += 256) s += row[k];
  s = wredsumi(s);
  __shared__ int ws[4];
  if ((threadIdx.x & 63) == 0) ws[threadIdx.x >> 6] = s;
  __syncthreads();
  if (threadIdx.x == 0) totals[b] = ws[0] + ws[1] + ws[2] + ws[3];
}

// scan of per-bucket totals (single small block)
__global__ __launch_bounds__(512) void k_bases2(
    const int* __restrict__ totals, int NB, int total,
    int* __restrict__ bases, int* __restrict__ offs, int N)
{
  __shared__ int sc[512];
  const int t = threadIdx.x;
  int v = (t < NB) ? totals[t] : 0;
  sc[t] = v; __syncthreads();
  for (int off = 1; off < 512; off <<= 1){
    int a = (t >= off) ? sc[t - off] : 0;
    __syncthreads();
    sc[t] += a;
    __syncthreads();
  }
  if (t < NB) bases[t] = sc[t] - v;
  if (t == 0) offs[N] = total;
}

__global__ __launch_bounds__(512) void k_bucket(
    const unsigned* __restrict__ temp, const int* __restrict__ tcounts,
    const int* __restrict__ trunstart, const int* __restrict__ bases,
    int C1, int N, int* __restrict__ ssrc, int* __restrict__ offs)
{
  __shared__ int rloc[1024], rlen[1024];
  __shared__ int cnt[256], sc[256];
  const int b = blockIdx.x, t = threadIdx.x;
  const int bb = bases[b];
  const int node0 = b << 8;
  const int nnode = min(256, N - node0);

  for (int k = t; k < C1; k += 512){
    rlen[k] = tcounts[(size_t)b * C1 + k];
    rloc[k] = k * K1E + trunstart[(size_t)b * C1 + k];
  }
  if (t < 256) cnt[t] = 0;
  __syncthreads();
  for (int r = t; r < C1; r += 512){
    const int L = rlen[r], base = rloc[r];
    for (int q = 0; q < L; ++q) atomicAdd(&cnt[temp[base + q] >> 17], 1);
  }
  __syncthreads();
  if (t < 256) sc[t] = cnt[t];
  __syncthreads();
  for (int off = 1; off < 256; off <<= 1){
    int a = (t < 256 && t >= off) ? sc[t - off] : 0;
    __syncthreads();
    if (t < 256) sc[t] += a;
    __syncthreads();
  }
  if (t < 256){
    int ex = sc[t] - cnt[t];
    if (t < nnode) offs[node0 + t] = bb + ex;
    cnt[t] = ex;
  }
  __syncthreads();
  for (int r = t; r < C1; r += 512){
    const int L = rlen[r], base = rloc[r];
    for (int q = 0; q < L; ++q){
      unsigned v = temp[base + q];
      int p = atomicAdd(&cnt[v >> 17], 1);
      ssrc[bb + p] = (int)(v & 0x1FFFFu);
    }
  }
}

// ---------------- fused linear + score kernel (fp16 h output) ----------------
template<int FIN, int FOUT>
__global__ __launch_bounds__(256) void k_linear(
    const float* __restrict__ x, const float* __restrict__ W,
    const float* __restrict__ a_s, const float* __restrict__ a_d,
    __half* __restrict__ h16, float* __restrict__ s_src, float* __restrict__ s_dst, int n)
{
  constexpr int CK = 32;
  constexpr int NCH = FIN / CK;
  __shared__ float xs[CK][257];
  const int tid = threadIdx.x;
  const int node0 = blockIdx.x * 256;
  const int node = node0 + tid;
  const int nrow = min(256, n - node0);

  float acc[FOUT];
#pragma unroll
  for (int o = 0; o < FOUT; ++o) acc[o] = 0.f;

  for (int kc = 0; kc < NCH; ++kc){
    __syncthreads();
    const int r0 = tid >> 3;
    const int c4 = tid & 7;
#pragma unroll
    for (int p = 0; p < 8; ++p){
      int row = p * 32 + r0;
      if (row < nrow){
        const float4 v = *reinterpret_cast<const float4*>(
            x + (size_t)(node0 + row) * FIN + kc * CK + c4 * 4);
        xs[c4 * 4 + 0][row] = v.x;
        xs[c4 * 4 + 1][row] = v.y;
        xs[c4 * 4 + 2][row] = v.z;
        xs[c4 * 4 + 3][row] = v.w;
      }
    }
    __syncthreads();
#pragma unroll 8
    for (int k = 0; k < CK; ++k){
      float xv = xs[k][tid];
      const int kg = kc * CK + k;
#pragma unroll
      for (int o4 = 0; o4 < FOUT / 4; ++o4){
        const float4 w = *reinterpret_cast<const float4*>(W + (size_t)kg * FOUT + o4 * 4);
        acc[o4 * 4 + 0] = fmaf(xv, w.x, acc[o4 * 4 + 0]);
        acc[o4 * 4 + 1] = fmaf(xv, w.y, acc[o4 * 4 + 1]);
        acc[o4 * 4 + 2] = fmaf(xv, w.z, acc[o4 * 4 + 2]);
        acc[o4 * 4 + 3] = fmaf(xv, w.w, acc[o4 * 4 + 3]);
      }
    }
  }

  if (node < n){
    float vs = 0.f, vd = 0.f;
#pragma unroll
    for (int o4 = 0; o4 < FOUT / 4; ++o4){
      const float4 as = *reinterpret_cast<const float4*>(a_s + o4 * 4);
      const float4 ad = *reinterpret_cast<const float4*>(a_d + o4 * 4);
      vs += acc[o4*4+0]*as.x + acc[o4*4+1]*as.y + acc[o4*4+2]*as.z + acc[o4*4+3]*as.w;
      vd += acc[o4*4+0]*ad.x + acc[o4*4+1]*ad.y + acc[o4*4+2]*ad.z + acc[o4*4+3]*ad.w;
    }
#pragma unroll
    for (int c = 0; c < FOUT / 8; ++c){
      uint4 u;
      u.x = pk2(acc[c*8+0], acc[c*8+1]);
      u.y = pk2(acc[c*8+2], acc[c*8+3]);
      u.z = pk2(acc[c*8+4], acc[c*8+5]);
      u.w = pk2(acc[c*8+6], acc[c*8+7]);
      *reinterpret_cast<uint4*>(h16 + (size_t)node * FOUT + c * 8) = u;
    }
    s_src[node] = vs;
    s_dst[node] = vd;
  }
}

// ---------------- segment softmax + aggregate (fp16 h gather) ----------------
template<int F, bool ELU>
__global__ __launch_bounds__(256) void k_segment(
    const int* __restrict__ offs, const int* __restrict__ ssrc,
    const float* __restrict__ s_src, const float* __restrict__ s_dst,
    const __half* __restrict__ h16, const float* __restrict__ bias,
    float* __restrict__ out, float* __restrict__ gmv, float* __restrict__ invv, int n)
{
  int wid = (blockIdx.x * blockDim.x + threadIdx.x) >> 6;
  if (wid >= n) return;
  int lane = threadIdx.x & 63;
  int beg = offs[wid], end = offs[wid + 1];
  float sd = s_dst[wid];

  float m = -FLT_MAX, ss = 0.f;
  for (int j = beg + lane; j < end; j += 64){
    int s = ssrc[j];
    float e = s_src[s] + sd;
    e = (e > 0.f) ? e : 0.2f * e;
    if (e > m){ ss = ss * __expf(m - e) + 1.f; m = e; }
    else ss += __expf(e - m);
  }
  float gm = wredmax(m);
  float denom = wredsum(ss * __expf(m - gm));
  float inv = 1.f / denom;
  if (lane == 0){ gmv[wid] = gm; invv[wid] = inv; }

  constexpr int FG = F / 8;
  constexpr int ES = 64 / FG;
  int es = lane / FG, fg = lane % FG;
  float a0=0.f,a1=0.f,a2=0.f,a3=0.f,a4=0.f,a5=0.f,a6=0.f,a7=0.f;
  for (int j = beg; j < end; j += ES){
    int jj = j + es;
    if (jj < end){
      int s = ssrc[jj];
      float e = s_src[s] + sd;
      e = (e > 0.f) ? e : 0.2f * e;
      float w = __expf(e - gm) * inv;
      const uint4 hv = *reinterpret_cast<const uint4*>(h16 + (size_t)s * F + fg * 8);
      float2 f0 = upk2(hv.x), f1 = upk2(hv.y), f2 = upk2(hv.z), f3 = upk2(hv.w);
      a0 = fmaf(w, f0.x, a0); a1 = fmaf(w, f0.y, a1);
      a2 = fmaf(w, f1.x, a2); a3 = fmaf(w, f1.y, a3);
      a4 = fmaf(w, f2.x, a4); a5 = fmaf(w, f2.y, a5);
      a6 = fmaf(w, f3.x, a6); a7 = fmaf(w, f3.y, a7);
    }
  }
#pragma unroll
  for (int mm = FG; mm < 64; mm <<= 1){
    a0 += __shfl_xor(a0, mm, 64); a1 += __shfl_xor(a1, mm, 64);
    a2 += __shfl_xor(a2, mm, 64); a3 += __shfl_xor(a3, mm, 64);
    a4 += __shfl_xor(a4, mm, 64); a5 += __shfl_xor(a5, mm, 64);
    a6 += __shfl_xor(a6, mm, 64); a7 += __shfl_xor(a7, mm, 64);
  }
  if (lane < FG){
    float o[8] = {a0,a1,a2,a3,a4,a5,a6,a7};
#pragma unroll
    for (int q = 0; q < 8; ++q){
      float v = o[q] + bias[fg * 8 + q];
      if (ELU) v = (v > 0.f) ? v : (__expf(v) - 1.f);
      o[q] = v;
    }
    float4 w0 = {o[0],o[1],o[2],o[3]}, w1 = {o[4],o[5],o[6],o[7]};
    *reinterpret_cast<float4*>(out + (size_t)wid * F + fg * 8)     = w0;
    *reinterpret_cast<float4*>(out + (size_t)wid * F + fg * 8 + 4) = w1;
  }
}

// ---------------- pack per-node softmax state (coalesced) ----------------
__global__ __launch_bounds__(256) void k_pack(
    const float* __restrict__ ss1, const float* __restrict__ sd1,
    const float* __restrict__ gm1, const float* __restrict__ inv1,
    const float* __restrict__ ss2, const float* __restrict__ sd2,
    const float* __restrict__ gm2, const float* __restrict__ inv2,
    float2* __restrict__ ssp, float4* __restrict__ pkd, int N)
{
  int i = blockIdx.x * blockDim.x + threadIdx.x;
  if (i >= N) return;
  ssp[i] = make_float2(ss1[i], ss2[i]);
  pkd[2 * i]     = make_float4(sd1[i], gm1[i], inv1[i], sd2[i]);
  pkd[2 * i + 1] = make_float4(gm2[i], inv2[i], 0.f, 0.f);
}

// ---------------- alpha in original edge order (4 edges/thread ILP) ----------------
__global__ __launch_bounds__(256) void k_alpha(
    const int* __restrict__ ei, int E0, int total, int G,
    const float2* __restrict__ ssp, const float4* __restrict__ pkd,
    float* __restrict__ a1, float* __restrict__ a2)
{
  const int t = blockIdx.x * blockDim.x + threadIdx.x;
  int sv[4], dv[4];
  bool ok[4];
#pragma unroll
  for (int q = 0; q < 4; ++q){
    int i = t + q * G;
    ok[q] = i < total;
    if (ok[q]){
      if (i < E0){ sv[q] = ei[i]; dv[q] = ei[E0 + i]; }
      else { sv[q] = i - E0; dv[q] = sv[q]; }
    }
  }
  float2 ssv[4]; float4 da[4], db[4];
#pragma unroll
  for (int q = 0; q < 4; ++q){
    if (ok[q]){
      ssv[q] = ssp[sv[q]];
      da[q]  = pkd[2 * dv[q]];
      db[q]  = pkd[2 * dv[q] + 1];
    }
  }
#pragma unroll
  for (int q = 0; q < 4; ++q){
    if (ok[q]){
      int i = t + q * G;
      float e1 = ssv[q].x + da[q].x;
      e1 = (e1 > 0.f) ? e1 : 0.2f * e1;
      a1[i] = __expf(e1 - da[q].y) * da[q].z;
      float e2 = ssv[q].y + da[q].w;
      e2 = (e2 > 0.f) ? e2 : 0.2f * e2;
      a2[i] = __expf(e2 - db[q].x) * db[q].y;
    }
  }
}

// ---------------- launch ----------------
extern "C" void kernel_launch(void* const* d_in, const int* in_sizes, int n_in,
                              void* d_out, int out_size, void* d_ws, size_t ws_size,
                              hipStream_t stream)
{
  const float* x    = (const float*)d_in[0];
  const int*   ei   = (const int*)  d_in[1];
  const float* W1   = (const float*)d_in[2];
  const float* a_s1 = (const float*)d_in[3];
  const float* a_d1 = (const float*)d_in[4];
  const float* b1   = (const float*)d_in[5];
  const float* W2   = (const float*)d_in[6];
  const float* a_s2 = (const float*)d_in[7];
  const float* a_d2 = (const float*)d_in[8];
  const float* b2   = (const float*)d_in[9];

  const int N    = in_sizes[0] / 128;   // 100000 (< 2^17, packing requirement)
  const int E0   = in_sizes[1] / 2;
  const int Etot = E0 + N;
  const int NB   = (N + 255) >> 8;      // 391 buckets
  const int C1   = (Etot + K1E - 1) / K1E;

  float* out_h2 = (float*)d_out;
  float* out_a1 = out_h2 + (size_t)N * 32;
  float* out_a2 = out_a1 + Etot;

  char* wsp = (char*)d_ws; size_t woff = 0;
  auto alloc = [&](size_t bytes)->void*{
    void* p = wsp + woff; woff += (bytes + 255) & ~(size_t)255; return p;
  };
  unsigned* temp     = (unsigned*)alloc((size_t)C1 * K1E * 4);
  int*      tcounts  = (int*)  alloc((size_t)NB * C1 * 4);
  int*      trunstart= (int*)  alloc((size_t)NB * C1 * 4);
  int*      totals   = (int*)  alloc((size_t)(NB + 1) * 4);
  int*      bases    = (int*)  alloc((size_t)(NB + 1) * 4);
  int*      offs     = (int*)  alloc(((size_t)N + 1) * 4);
  int*      ssrc     = (int*)  alloc((size_t)Etot * 4);
  __half*   h1       = (__half*)alloc((size_t)N * 64 * 2);
  float*    g1       = (float*)alloc((size_t)N * 64 * 4);
  __half*   h2l      = (__half*)alloc((size_t)N * 32 * 2);
  float*    s1s      = (float*)alloc((size_t)N * 4);
  float*    s1d      = (float*)alloc((size_t)N * 4);
  float*    s2s      = (float*)alloc((size_t)N * 4);
  float*    s2d      = (float*)alloc((size_t)N * 4);
  float*    gm1      = (float*)alloc((size_t)N * 4);
  float*    inv1     = (float*)alloc((size_t)N * 4);
  float*    gm2      = (float*)alloc((size_t)N * 4);
  float*    inv2     = (float*)alloc((size_t)N * 4);
  float2*   ssp      = (float2*)alloc((size_t)N * 8);
  float4*   pkd      = (float4*)alloc((size_t)N * 32);

  const int tb = 256;
  k_split<<<C1, 256, 0, stream>>>(ei, E0, Etot, NB, C1, temp, tcounts, trunstart);
  k_rowsum<<<NB, 256, 0, stream>>>(tcounts, C1, totals);
  k_bases2<<<1, 512, 0, stream>>>(totals, NB, Etot, bases, offs, N);
  k_bucket<<<NB, 512, 0, stream>>>(temp, tcounts, trunstart, bases, C1, N, ssrc, offs);

  const int nlb = (N + 255) / 256;
  k_linear<128, 64><<<nlb, 256, 0, stream>>>(x, W1, a_s1, a_d1, h1, s1s, s1d, N);
  k_segment<64, true><<<(N + 3) / 4, 256, 0, stream>>>(offs, ssrc, s1s, s1d, h1, b1, g1, gm1, inv1, N);
  k_linear<64, 32><<<nlb, 256, 0, stream>>>(g1, W2, a_s2, a_d2, h2l, s2s, s2d, N);
  k_segment<32, false><<<(N + 3) / 4, 256, 0, stream>>>(offs, ssrc, s2s, s2d, h2l, b2, out_h2, gm2, inv2, N);

  k_pack<<<nlb, 256, 0, stream>>>(s1s, s1d, gm1, inv1, s2s, s2d, gm2, inv2, ssp, pkd, N);
  const int G = (Etot + 3) / 4;
  k_alpha<<<(G + tb - 1) / tb, tb, 0, stream>>>(ei, E0, Etot, G, ssp, pkd, out_a1, out_a2);
}

// Round 9
// 360.471 us; speedup vs baseline: 4.0937x; 1.0191x over previous
//
#include <hip/hip_runtime.h>
#include <hip/hip_fp16.h>
#include <float.h>

#define K1E 6528   // edges per k_split block (13KB u32 stage + 4KB counters in LDS)

__device__ __forceinline__ float wredmax(float v){
#pragma unroll
  for (int m = 32; m >= 1; m >>= 1) v = fmaxf(v, __shfl_xor(v, m, 64));
  return v;
}
__device__ __forceinline__ float wredsum(float v){
#pragma unroll
  for (int m = 32; m >= 1; m >>= 1) v += __shfl_xor(v, m, 64);
  return v;
}
__device__ __forceinline__ int wredsumi(int v){
#pragma unroll
  for (int m = 32; m >= 1; m >>= 1) v += __shfl_xor(v, m, 64);
  return v;
}
__device__ __forceinline__ unsigned pk2(float a, float b){
  __half2 t = __floats2half2_rn(a, b);
  return __builtin_bit_cast(unsigned, t);
}

// ---------------- CSR build: deterministic two-level counting sort ----------------
__global__ __launch_bounds__(256) void k_split(
    const int* __restrict__ ei, int E0, int total, int NB, int C1,
    unsigned* __restrict__ temp, int* __restrict__ tcounts, int* __restrict__ trunstart)
{
  __shared__ int cnt[512];
  __shared__ int pref[512];
  __shared__ unsigned stage[K1E];
  const int tid = threadIdx.x, blk = blockIdx.x;
  const int lo = blk * K1E, hi = min(lo + K1E, total);

  for (int i = tid; i < 512; i += 256) cnt[i] = 0;
  __syncthreads();
  for (int i = lo + tid; i < hi; i += 256){
    int d = (i < E0) ? ei[E0 + i] : (i - E0);
    atomicAdd(&cnt[d >> 8], 1);
  }
  __syncthreads();
  for (int i = tid; i < 512; i += 256) pref[i] = cnt[i];
  __syncthreads();
  for (int off = 1; off < 512; off <<= 1){
    int a0 = (tid >= off) ? pref[tid - off] : 0;
    int a1 = pref[tid + 256 - off];
    __syncthreads();
    pref[tid] += a0;
    pref[tid + 256] += a1;
    __syncthreads();
  }
  for (int i = tid; i < NB; i += 256){
    int c = cnt[i];
    int ex = pref[i] - c;
    tcounts[(size_t)i * C1 + blk] = c;
    trunstart[(size_t)i * C1 + blk] = ex;
    cnt[i] = ex;
  }
  __syncthreads();
  for (int i = lo + tid; i < hi; i += 256){
    int s, d;
    if (i < E0){ s = ei[i]; d = ei[E0 + i]; } else { s = i - E0; d = s; }
    int p = atomicAdd(&cnt[d >> 8], 1);
    stage[p] = ((unsigned)(d & 255) << 17) | (unsigned)s;
  }
  __syncthreads();
  for (int i = tid; i < hi - lo; i += 256) temp[(size_t)lo + i] = stage[i];
}

// per-bucket totals: one block per bucket, coalesced row sum
__global__ __launch_bounds__(256) void k_rowsum(
    const int* __restrict__ tcounts, int C1, int* __restrict__ totals)
{
  const int b = blockIdx.x;
  const int* row = tcounts + (size_t)b * C1;
  int s = 0;
  for (int k = threadIdx.x; k < C1; k += 256) s += row[k];
  s = wredsumi(s);
  __shared__ int ws[4];
  if ((threadIdx.x & 63) == 0) ws[threadIdx.x >> 6] = s;
  __syncthreads();
  if (threadIdx.x == 0) totals[b] = ws[0] + ws[1] + ws[2] + ws[3];
}

// scan of per-bucket totals (single small block)
__global__ __launch_bounds__(512) void k_bases2(
    const int* __restrict__ totals, int NB, int total,
    int* __restrict__ bases, int* __restrict__ offs, int N)
{
  __shared__ int sc[512];
  const int t = threadIdx.x;
  int v = (t < NB) ? totals[t] : 0;
  sc[t] = v; __syncthreads();
  for (int off = 1; off < 512; off <<= 1){
    int a = (t >= off) ? sc[t - off] : 0;
    __syncthreads();
    sc[t] += a;
    __syncthreads();
  }
  if (t < NB) bases[t] = sc[t] - v;
  if (t == 0) offs[N] = total;
}

__global__ __launch_bounds__(512) void k_bucket(
    const unsigned* __restrict__ temp, const int* __restrict__ tcounts,
    const int* __restrict__ trunstart, const int* __restrict__ bases,
    int C1, int N, int* __restrict__ ssrc, int* __restrict__ offs)
{
  __shared__ int rloc[1024], rlen[1024];
  __shared__ int cnt[256], sc[256];
  const int b = blockIdx.x, t = threadIdx.x;
  const int bb = bases[b];
  const int node0 = b << 8;
  const int nnode = min(256, N - node0);

  for (int k = t; k < C1; k += 512){
    rlen[k] = tcounts[(size_t)b * C1 + k];
    rloc[k] = k * K1E + trunstart[(size_t)b * C1 + k];
  }
  if (t < 256) cnt[t] = 0;
  __syncthreads();
  for (int r = t; r < C1; r += 512){
    const int L = rlen[r], base = rloc[r];
    for (int q = 0; q < L; ++q) atomicAdd(&cnt[temp[base + q] >> 17], 1);
  }
  __syncthreads();
  if (t < 256) sc[t] = cnt[t];
  __syncthreads();
  for (int off = 1; off < 256; off <<= 1){
    int a = (t < 256 && t >= off) ? sc[t - off] : 0;
    __syncthreads();
    if (t < 256) sc[t] += a;
    __syncthreads();
  }
  if (t < 256){
    int ex = sc[t] - cnt[t];
    if (t < nnode) offs[node0 + t] = bb + ex;
    cnt[t] = ex;
  }
  __syncthreads();
  for (int r = t; r < C1; r += 512){
    const int L = rlen[r], base = rloc[r];
    for (int q = 0; q < L; ++q){
      unsigned v = temp[base + q];
      int p = atomicAdd(&cnt[v >> 17], 1);
      ssrc[bb + p] = (int)(v & 0x1FFFFu);
    }
  }
}

// ---------------- fused linear + score kernel (fp16 h output) ----------------
template<int FIN, int FOUT>
__global__ __launch_bounds__(256) void k_linear(
    const float* __restrict__ x, const float* __restrict__ W,
    const float* __restrict__ a_s, const float* __restrict__ a_d,
    __half* __restrict__ h16, float* __restrict__ s_src, float* __restrict__ s_dst, int n)
{
  constexpr int CK = 32;
  constexpr int NCH = FIN / CK;
  __shared__ float xs[CK][257];
  const int tid = threadIdx.x;
  const int node0 = blockIdx.x * 256;
  const int node = node0 + tid;
  const int nrow = min(256, n - node0);

  float acc[FOUT];
#pragma unroll
  for (int o = 0; o < FOUT; ++o) acc[o] = 0.f;

  for (int kc = 0; kc < NCH; ++kc){
    __syncthreads();
    const int r0 = tid >> 3;
    const int c4 = tid & 7;
#pragma unroll
    for (int p = 0; p < 8; ++p){
      int row = p * 32 + r0;
      if (row < nrow){
        const float4 v = *reinterpret_cast<const float4*>(
            x + (size_t)(node0 + row) * FIN + kc * CK + c4 * 4);
        xs[c4 * 4 + 0][row] = v.x;
        xs[c4 * 4 + 1][row] = v.y;
        xs[c4 * 4 + 2][row] = v.z;
        xs[c4 * 4 + 3][row] = v.w;
      }
    }
    __syncthreads();
#pragma unroll 8
    for (int k = 0; k < CK; ++k){
      float xv = xs[k][tid];
      const int kg = kc * CK + k;
#pragma unroll
      for (int o4 = 0; o4 < FOUT / 4; ++o4){
        const float4 w = *reinterpret_cast<const float4*>(W + (size_t)kg * FOUT + o4 * 4);
        acc[o4 * 4 + 0] = fmaf(xv, w.x, acc[o4 * 4 + 0]);
        acc[o4 * 4 + 1] = fmaf(xv, w.y, acc[o4 * 4 + 1]);
        acc[o4 * 4 + 2] = fmaf(xv, w.z, acc[o4 * 4 + 2]);
        acc[o4 * 4 + 3] = fmaf(xv, w.w, acc[o4 * 4 + 3]);
      }
    }
  }

  if (node < n){
    float vs = 0.f, vd = 0.f;
#pragma unroll
    for (int o4 = 0; o4 < FOUT / 4; ++o4){
      const float4 as = *reinterpret_cast<const float4*>(a_s + o4 * 4);
      const float4 ad = *reinterpret_cast<const float4*>(a_d + o4 * 4);
      vs += acc[o4*4+0]*as.x + acc[o4*4+1]*as.y + acc[o4*4+2]*as.z + acc[o4*4+3]*as.w;
      vd += acc[o4*4+0]*ad.x + acc[o4*4+1]*ad.y + acc[o4*4+2]*ad.z + acc[o4*4+3]*ad.w;
    }
#pragma unroll
    for (int c = 0; c < FOUT / 8; ++c){
      uint4 u;
      u.x = pk2(acc[c*8+0], acc[c*8+1]);
      u.y = pk2(acc[c*8+2], acc[c*8+3]);
      u.z = pk2(acc[c*8+4], acc[c*8+5]);
      u.w = pk2(acc[c*8+6], acc[c*8+7]);
      *reinterpret_cast<uint4*>(h16 + (size_t)node * FOUT + c * 8) = u;
    }
    s_src[node] = vs;
    s_dst[node] = vd;
  }
}

// ---------------- segment softmax + aggregate (LDS e-cache + fp16 pk-fma) ----------------
template<int F, bool ELU>
__global__ __launch_bounds__(256) void k_segment(
    const int* __restrict__ offs, const int* __restrict__ ssrc,
    const float* __restrict__ s_src, const float* __restrict__ s_dst,
    const __half* __restrict__ h16, const float* __restrict__ bias,
    float* __restrict__ out, float* __restrict__ gmv, float* __restrict__ invv, int n)
{
  constexpr int CAP = 128;
  __shared__ float ew[4][CAP];
  const int wv = threadIdx.x >> 6;
  const int lane = threadIdx.x & 63;
  const int wid = (blockIdx.x * blockDim.x + threadIdx.x) >> 6;
  const bool act = wid < n;
  int beg = 0, end = 0;
  float sd = 0.f;
  if (act){ beg = offs[wid]; end = offs[wid + 1]; sd = s_dst[wid]; }
  const int deg = end - beg;
  const bool fit = deg <= CAP;            // wave-uniform

  // pass A: online (max, scaled-sum); cache post-leaky scores in LDS
  float m = -FLT_MAX, ssum = 0.f;
  for (int j = beg + lane; j < end; j += 64){
    int s = ssrc[j];
    float e = s_src[s] + sd;
    e = (e > 0.f) ? e : 0.2f * e;
    if (fit) ew[wv][j - beg] = e;
    if (e > m){ ssum = ssum * __expf(m - e) + 1.f; m = e; }
    else ssum += __expf(e - m);
  }
  asm volatile("s_waitcnt lgkmcnt(0)" ::: "memory");   // wave-local ew visibility
  float gm = wredmax(m);
  float denom = wredsum(ssum * __expf(m - gm));
  float inv = 1.f / denom;
  if (act && lane == 0){ gmv[wid] = gm; invv[wid] = inv; }

  // pass B: FG lanes per edge (uint4 = 8 halves), ES edges in flight, pk-fma accumulate
  constexpr int FG = F / 8;
  constexpr int ES = 64 / FG;
  const int es = lane / FG, fg = lane % FG;
  __half2 hc0 = __float2half2_rn(0.f), hc1 = hc0, hc2 = hc0, hc3 = hc0;
  for (int j = beg; j < end; j += ES){
    int jj = j + es;
    if (jj < end){
      int s = ssrc[jj];
      float e;
      if (fit) e = ew[wv][jj - beg];
      else { e = s_src[s] + sd; e = (e > 0.f) ? e : 0.2f * e; }
      float w = __expf(e - gm) * inv;
      __half2 w2 = __float2half2_rn(w);
      const uint4 hv = *reinterpret_cast<const uint4*>(h16 + (size_t)s * F + fg * 8);
      hc0 = __hfma2(w2, __builtin_bit_cast(__half2, hv.x), hc0);
      hc1 = __hfma2(w2, __builtin_bit_cast(__half2, hv.y), hc1);
      hc2 = __hfma2(w2, __builtin_bit_cast(__half2, hv.z), hc2);
      hc3 = __hfma2(w2, __builtin_bit_cast(__half2, hv.w), hc3);
    }
  }
  float2 p0 = __half22float2(hc0), p1 = __half22float2(hc1),
         p2 = __half22float2(hc2), p3 = __half22float2(hc3);
  float a0 = p0.x, a1 = p0.y, a2 = p1.x, a3 = p1.y,
        a4 = p2.x, a5 = p2.y, a6 = p3.x, a7 = p3.y;
#pragma unroll
  for (int mm = FG; mm < 64; mm <<= 1){
    a0 += __shfl_xor(a0, mm, 64); a1 += __shfl_xor(a1, mm, 64);
    a2 += __shfl_xor(a2, mm, 64); a3 += __shfl_xor(a3, mm, 64);
    a4 += __shfl_xor(a4, mm, 64); a5 += __shfl_xor(a5, mm, 64);
    a6 += __shfl_xor(a6, mm, 64); a7 += __shfl_xor(a7, mm, 64);
  }
  if (act && lane < FG){
    float o[8] = {a0,a1,a2,a3,a4,a5,a6,a7};
#pragma unroll
    for (int q = 0; q < 8; ++q){
      float v = o[q] + bias[fg * 8 + q];
      if (ELU) v = (v > 0.f) ? v : (__expf(v) - 1.f);
      o[q] = v;
    }
    float4 w0 = {o[0],o[1],o[2],o[3]}, w1 = {o[4],o[5],o[6],o[7]};
    *reinterpret_cast<float4*>(out + (size_t)wid * F + fg * 8)     = w0;
    *reinterpret_cast<float4*>(out + (size_t)wid * F + fg * 8 + 4) = w1;
  }
}

// ---------------- pack per-node softmax state (coalesced) ----------------
__global__ __launch_bounds__(256) void k_pack(
    const float* __restrict__ ss1, const float* __restrict__ sd1,
    const float* __restrict__ gm1, const float* __restrict__ inv1,
    const float* __restrict__ ss2, const float* __restrict__ sd2,
    const float* __restrict__ gm2, const float* __restrict__ inv2,
    float2* __restrict__ ssp, float4* __restrict__ pkd, int N)
{
  int i = blockIdx.x * blockDim.x + threadIdx.x;
  if (i >= N) return;
  ssp[i] = make_float2(ss1[i], ss2[i]);
  pkd[2 * i]     = make_float4(sd1[i], gm1[i], inv1[i], sd2[i]);
  pkd[2 * i + 1] = make_float4(gm2[i], inv2[i], 0.f, 0.f);
}

// ---------------- alpha in original edge order (4 edges/thread ILP) ----------------
__global__ __launch_bounds__(256) void k_alpha(
    const int* __restrict__ ei, int E0, int total, int G,
    const float2* __restrict__ ssp, const float4* __restrict__ pkd,
    float* __restrict__ a1, float* __restrict__ a2)
{
  const int t = blockIdx.x * blockDim.x + threadIdx.x;
  int sv[4], dv[4];
  bool ok[4];
#pragma unroll
  for (int q = 0; q < 4; ++q){
    int i = t + q * G;
    ok[q] = i < total;
    if (ok[q]){
      if (i < E0){ sv[q] = ei[i]; dv[q] = ei[E0 + i]; }
      else { sv[q] = i - E0; dv[q] = sv[q]; }
    }
  }
  float2 ssv[4]; float4 da[4], db[4];
#pragma unroll
  for (int q = 0; q < 4; ++q){
    if (ok[q]){
      ssv[q] = ssp[sv[q]];
      da[q]  = pkd[2 * dv[q]];
      db[q]  = pkd[2 * dv[q] + 1];
    }
  }
#pragma unroll
  for (int q = 0; q < 4; ++q){
    if (ok[q]){
      int i = t + q * G;
      float e1 = ssv[q].x + da[q].x;
      e1 = (e1 > 0.f) ? e1 : 0.2f * e1;
      a1[i] = __expf(e1 - da[q].y) * da[q].z;
      float e2 = ssv[q].y + da[q].w;
      e2 = (e2 > 0.f) ? e2 : 0.2f * e2;
      a2[i] = __expf(e2 - db[q].x) * db[q].y;
    }
  }
}

// ---------------- launch ----------------
extern "C" void kernel_launch(void* const* d_in, const int* in_sizes, int n_in,
                              void* d_out, int out_size, void* d_ws, size_t ws_size,
                              hipStream_t stream)
{
  const float* x    = (const float*)d_in[0];
  const int*   ei   = (const int*)  d_in[1];
  const float* W1   = (const float*)d_in[2];
  const float* a_s1 = (const float*)d_in[3];
  const float* a_d1 = (const float*)d_in[4];
  const float* b1   = (const float*)d_in[5];
  const float* W2   = (const float*)d_in[6];
  const float* a_s2 = (const float*)d_in[7];
  const float* a_d2 = (const float*)d_in[8];
  const float* b2   = (const float*)d_in[9];

  const int N    = in_sizes[0] / 128;   // 100000 (< 2^17, packing requirement)
  const int E0   = in_sizes[1] / 2;
  const int Etot = E0 + N;
  const int NB   = (N + 255) >> 8;      // 391 buckets
  const int C1   = (Etot + K1E - 1) / K1E;

  float* out_h2 = (float*)d_out;
  float* out_a1 = out_h2 + (size_t)N * 32;
  float* out_a2 = out_a1 + Etot;

  char* wsp = (char*)d_ws; size_t woff = 0;
  auto alloc = [&](size_t bytes)->void*{
    void* p = wsp + woff; woff += (bytes + 255) & ~(size_t)255; return p;
  };
  unsigned* temp     = (unsigned*)alloc((size_t)C1 * K1E * 4);
  int*      tcounts  = (int*)  alloc((size_t)NB * C1 * 4);
  int*      trunstart= (int*)  alloc((size_t)NB * C1 * 4);
  int*      totals   = (int*)  alloc((size_t)(NB + 1) * 4);
  int*      bases    = (int*)  alloc((size_t)(NB + 1) * 4);
  int*      offs     = (int*)  alloc(((size_t)N + 1) * 4);
  int*      ssrc     = (int*)  alloc((size_t)Etot * 4);
  __half*   h1       = (__half*)alloc((size_t)N * 64 * 2);
  float*    g1       = (float*)alloc((size_t)N * 64 * 4);
  __half*   h2l      = (__half*)alloc((size_t)N * 32 * 2);
  float*    s1s      = (float*)alloc((size_t)N * 4);
  float*    s1d      = (float*)alloc((size_t)N * 4);
  float*    s2s      = (float*)alloc((size_t)N * 4);
  float*    s2d      = (float*)alloc((size_t)N * 4);
  float*    gm1      = (float*)alloc((size_t)N * 4);
  float*    inv1     = (float*)alloc((size_t)N * 4);
  float*    gm2      = (float*)alloc((size_t)N * 4);
  float*    inv2     = (float*)alloc((size_t)N * 4);
  float2*   ssp      = (float2*)alloc((size_t)N * 8);
  float4*   pkd      = (float4*)alloc((size_t)N * 32);

  const int tb = 256;
  k_split<<<C1, 256, 0, stream>>>(ei, E0, Etot, NB, C1, temp, tcounts, trunstart);
  k_rowsum<<<NB, 256, 0, stream>>>(tcounts, C1, totals);
  k_bases2<<<1, 512, 0, stream>>>(totals, NB, Etot, bases, offs, N);
  k_bucket<<<NB, 512, 0, stream>>>(temp, tcounts, trunstart, bases, C1, N, ssrc, offs);

  const int nlb = (N + 255) / 256;
  k_linear<128, 64><<<nlb, 256, 0, stream>>>(x, W1, a_s1, a_d1, h1, s1s, s1d, N);
  k_segment<64, true><<<(N + 3) / 4, 256, 0, stream>>>(offs, ssrc, s1s, s1d, h1, b1, g1, gm1, inv1, N);
  k_linear<64, 32><<<nlb, 256, 0, stream>>>(g1, W2, a_s2, a_d2, h2l, s2s, s2d, N);
  k_segment<32, false><<<(N + 3) / 4, 256, 0, stream>>>(offs, ssrc, s2s, s2d, h2l, b2, out_h2, gm2, inv2, N);

  k_pack<<<nlb, 256, 0, stream>>>(s1s, s1d, gm1, inv1, s2s, s2d, gm2, inv2, ssp, pkd, N);
  const int G = (Etot + 3) / 4;
  k_alpha<<<(G + tb - 1) / tb, tb, 0, stream>>>(ei, E0, Etot, G, ssp, pkd, out_a1, out_a2);
}